// Round 1
// baseline (2104.881 us; speedup 1.0000x reference)
//
#include <hip/hip_runtime.h>
#include <cstddef>

// Problem constants (reference: B=2, T=2048, D=1024, H=16, DH=64, NU=1024)
namespace {
constexpr int B_ = 2, T_ = 2048, D_ = 1024, H_ = 16, DH_ = 64, NU_ = 1024;
constexpr float SCALE = 0.03125f;           // NU^-0.5 = 1/32
constexpr size_t OUT_ELEMS = (size_t)B_ * T_ * NU_;   // 4,194,304
}

__device__ __forceinline__ float4 ld4(const float* p) { return *reinterpret_cast<const float4*>(p); }
__device__ __forceinline__ void st4(float* p, const float4 v) { *reinterpret_cast<float4*>(p) = v; }
__device__ __forceinline__ void fma4(float4& a, float s, const float4 v) {
    a.x = fmaf(s, v.x, a.x); a.y = fmaf(s, v.y, a.y);
    a.z = fmaf(s, v.z, a.z); a.w = fmaf(s, v.w, a.w);
}

// ---------------------------------------------------------------------------
// Kernel 1: QKV projection. Y = X @ W + bias, X:[4096,1024], W:[1024,1024].
// grid = (NU/128, M/128, 3); z selects (queries,Wq,bq)->q, (keys,Wk,bk)->k,
// (keys,Wv,bv)->v. 128x128 tile, BK=16, 8x8 micro-tile per thread.
// ---------------------------------------------------------------------------
__global__ __launch_bounds__(256) void proj_gemm_kernel(
    const float* __restrict__ queries, const float* __restrict__ keys,
    const float* __restrict__ Wq, const float* __restrict__ bq,
    const float* __restrict__ Wk, const float* __restrict__ bk,
    const float* __restrict__ Wv, const float* __restrict__ bv,
    float* __restrict__ qws, float* __restrict__ kws, float* __restrict__ vws)
{
    const int z = blockIdx.z;
    const float* __restrict__ X    = (z == 0) ? queries : keys;
    const float* __restrict__ W    = (z == 0) ? Wq : (z == 1) ? Wk : Wv;
    const float* __restrict__ bias = (z == 0) ? bq : (z == 1) ? bk : bv;
    float* __restrict__ Y          = (z == 0) ? qws : (z == 1) ? kws : vws;

    const int n0 = blockIdx.x * 128;
    const int m0 = blockIdx.y * 128;
    const int t  = threadIdx.x;
    const int tm = t >> 4, tn = t & 15;   // 16x16 thread grid, 8x8 micro

    __shared__ float As[16][132];   // As[k][m], padded
    __shared__ float Bs[16][132];   // Bs[k][n], padded

    float acc[8][8];
#pragma unroll
    for (int i = 0; i < 8; ++i)
#pragma unroll
        for (int j = 0; j < 8; ++j) acc[i][j] = 0.f;

    const int am  = t >> 1;          // 0..127 (A row within tile)
    const int ah  = (t & 1) * 8;     // k sub-offset 0 or 8
    const int bkr = t >> 4;          // 0..15  (B k-row)
    const int bn  = (t & 15) * 8;    // B col offset

    for (int k0 = 0; k0 < D_; k0 += 16) {
        float4 av0 = ld4(&X[(size_t)(m0 + am) * D_ + k0 + ah]);
        float4 av1 = ld4(&X[(size_t)(m0 + am) * D_ + k0 + ah + 4]);
        float4 bv0 = ld4(&W[(size_t)(k0 + bkr) * NU_ + n0 + bn]);
        float4 bv1 = ld4(&W[(size_t)(k0 + bkr) * NU_ + n0 + bn + 4]);
        // previous iteration's trailing __syncthreads protects these writes
        As[ah + 0][am] = av0.x; As[ah + 1][am] = av0.y;
        As[ah + 2][am] = av0.z; As[ah + 3][am] = av0.w;
        As[ah + 4][am] = av1.x; As[ah + 5][am] = av1.y;
        As[ah + 6][am] = av1.z; As[ah + 7][am] = av1.w;
        st4(&Bs[bkr][bn], bv0);
        st4(&Bs[bkr][bn + 4], bv1);
        __syncthreads();
#pragma unroll
        for (int kk = 0; kk < 16; ++kk) {
            float4 a0 = ld4(&As[kk][tm * 8]);
            float4 a1 = ld4(&As[kk][tm * 8 + 4]);
            float4 b0 = ld4(&Bs[kk][tn * 8]);
            float4 b1 = ld4(&Bs[kk][tn * 8 + 4]);
            float a_[8] = {a0.x, a0.y, a0.z, a0.w, a1.x, a1.y, a1.z, a1.w};
            float b_[8] = {b0.x, b0.y, b0.z, b0.w, b1.x, b1.y, b1.z, b1.w};
#pragma unroll
            for (int i = 0; i < 8; ++i)
#pragma unroll
                for (int j = 0; j < 8; ++j)
                    acc[i][j] = fmaf(a_[i], b_[j], acc[i][j]);
        }
        __syncthreads();
    }

    float4 e0 = ld4(&bias[n0 + tn * 8]);
    float4 e1 = ld4(&bias[n0 + tn * 8 + 4]);
    float be[8] = {e0.x, e0.y, e0.z, e0.w, e1.x, e1.y, e1.z, e1.w};
#pragma unroll
    for (int i = 0; i < 8; ++i) {
        float4 o0 = make_float4(acc[i][0] + be[0], acc[i][1] + be[1],
                                acc[i][2] + be[2], acc[i][3] + be[3]);
        float4 o1 = make_float4(acc[i][4] + be[4], acc[i][5] + be[5],
                                acc[i][6] + be[6], acc[i][7] + be[7]);
        st4(&Y[(size_t)(m0 + tm * 8 + i) * NU_ + n0 + tn * 8], o0);
        st4(&Y[(size_t)(m0 + tm * 8 + i) * NU_ + n0 + tn * 8 + 4], o1);
    }
}

// ---------------------------------------------------------------------------
// Kernel 2 (phase 0): per (b,h,64-row q-tile) compute unnormalized softmax
// row-sums and the PV output. Scores are bounded (|s|<~1 after *1/32), so
// exp without max-subtraction is numerically safe in fp32.
// grid = (T/64, B*H), 256 threads. Thread micro-tile: 4 rows x 4 cols
// (cols strided by 16 for bank-conflict-free LDS reads).
// ---------------------------------------------------------------------------
__global__ __launch_bounds__(256) void attn_phase0_kernel(
    const float* __restrict__ qws, const float* __restrict__ kws,
    const float* __restrict__ vws, float* __restrict__ rsws,
    float* __restrict__ out)
{
    const int tile = blockIdx.x;          // q-row tile: rows [r0, r0+64)
    const int bh   = blockIdx.y;          // b*H + h
    const int b = bh >> 4, h = bh & 15;
    const int r0 = tile * 64;
    const int t  = threadIdx.x;
    const int tr = t >> 4, tc = t & 15;   // rows tr*4+rr, cols tc + c*16

    __shared__ float Qs[64][68];
    __shared__ float Ks[64][68];
    __shared__ float Ss[64][68];
    __shared__ float rs[64];

    {   // load Q tile (64 rows x 64 dims of this head)
        const int row = t >> 2, c16 = (t & 3) * 16;
        const float* src = &qws[(size_t)(b * T_ + r0 + row) * NU_ + h * DH_ + c16];
        st4(&Qs[row][c16 + 0],  ld4(src + 0));
        st4(&Qs[row][c16 + 4],  ld4(src + 4));
        st4(&Qs[row][c16 + 8],  ld4(src + 8));
        st4(&Qs[row][c16 + 12], ld4(src + 12));
    }
    if (t < 64) rs[t] = 0.f;

    float4 acc4[4];
#pragma unroll
    for (int rr = 0; rr < 4; ++rr) acc4[rr] = make_float4(0.f, 0.f, 0.f, 0.f);

    __syncthreads();

    const int nch = tile + 1;             // causal: only chunks with j <= r0+63
    for (int ch = 0; ch < nch; ++ch) {
        const int jc = ch * 64;
        {   // stage K chunk
            const int row = t >> 2, c16 = (t & 3) * 16;
            const float* src = &kws[(size_t)(b * T_ + jc + row) * NU_ + h * DH_ + c16];
            st4(&Ks[row][c16 + 0],  ld4(src + 0));
            st4(&Ks[row][c16 + 4],  ld4(src + 4));
            st4(&Ks[row][c16 + 8],  ld4(src + 8));
            st4(&Ks[row][c16 + 12], ld4(src + 12));
        }
        __syncthreads();

        // ---- scores: s[rr][c] = Q[row] . K[col] ----
        float s[4][4];
#pragma unroll
        for (int rr = 0; rr < 4; ++rr)
#pragma unroll
            for (int c = 0; c < 4; ++c) s[rr][c] = 0.f;

#pragma unroll
        for (int d4 = 0; d4 < 16; ++d4) {
            float4 q[4], kf[4];
#pragma unroll
            for (int rr = 0; rr < 4; ++rr) q[rr] = ld4(&Qs[tr * 4 + rr][d4 * 4]);
#pragma unroll
            for (int c = 0; c < 4; ++c) kf[c] = ld4(&Ks[tc + c * 16][d4 * 4]);
#pragma unroll
            for (int rr = 0; rr < 4; ++rr)
#pragma unroll
                for (int c = 0; c < 4; ++c) {
                    s[rr][c] = fmaf(q[rr].x, kf[c].x, s[rr][c]);
                    s[rr][c] = fmaf(q[rr].y, kf[c].y, s[rr][c]);
                    s[rr][c] = fmaf(q[rr].z, kf[c].z, s[rr][c]);
                    s[rr][c] = fmaf(q[rr].w, kf[c].w, s[rr][c]);
                }
        }

        // ---- exp + causal mask; stash e in LDS; row-sum partials ----
        float psum[4] = {0.f, 0.f, 0.f, 0.f};
#pragma unroll
        for (int rr = 0; rr < 4; ++rr) {
            const int i = r0 + tr * 4 + rr;
#pragma unroll
            for (int c = 0; c < 4; ++c) {
                const int j = jc + tc + c * 16;
                const float e = (j <= i) ? __expf(s[rr][c] * SCALE) : 0.f;
                Ss[tr * 4 + rr][tc + c * 16] = e;
                psum[rr] += e;
            }
        }
        // reduce across the 16 tc lanes (xor masks stay inside the group)
#pragma unroll
        for (int rr = 0; rr < 4; ++rr) {
            psum[rr] += __shfl_xor(psum[rr], 1);
            psum[rr] += __shfl_xor(psum[rr], 2);
            psum[rr] += __shfl_xor(psum[rr], 4);
            psum[rr] += __shfl_xor(psum[rr], 8);
        }
        if (tc == 0) {
#pragma unroll
            for (int rr = 0; rr < 4; ++rr) rs[tr * 4 + rr] += psum[rr];
        }
        __syncthreads();   // Ss ready for PV; rs adds done

        // ---- PV: acc[row][d] += e[row][j] * V[j][d]; V straight from L2 ----
        const float* vbase = &vws[(size_t)(b * T_ + jc) * NU_ + h * DH_ + tc * 4];
#pragma unroll 4
        for (int j4 = 0; j4 < 16; ++j4) {
            float4 sv[4];
#pragma unroll
            for (int rr = 0; rr < 4; ++rr) sv[rr] = ld4(&Ss[tr * 4 + rr][j4 * 4]);
            float4 v0 = ld4(&vbase[(size_t)(j4 * 4 + 0) * NU_]);
            float4 v1 = ld4(&vbase[(size_t)(j4 * 4 + 1) * NU_]);
            float4 v2 = ld4(&vbase[(size_t)(j4 * 4 + 2) * NU_]);
            float4 v3 = ld4(&vbase[(size_t)(j4 * 4 + 3) * NU_]);
#pragma unroll
            for (int rr = 0; rr < 4; ++rr) {
                fma4(acc4[rr], sv[rr].x, v0);
                fma4(acc4[rr], sv[rr].y, v1);
                fma4(acc4[rr], sv[rr].z, v2);
                fma4(acc4[rr], sv[rr].w, v3);
            }
        }
        __syncthreads();   // protect Ks/Ss overwrite next chunk
    }

    // finalize: out = acc / rowsum; persist rowsums for phase 1
    float inv[4];
#pragma unroll
    for (int rr = 0; rr < 4; ++rr) inv[rr] = 1.f / rs[tr * 4 + rr];
#pragma unroll
    for (int rr = 0; rr < 4; ++rr) {
        float4 o = make_float4(acc4[rr].x * inv[rr], acc4[rr].y * inv[rr],
                               acc4[rr].z * inv[rr], acc4[rr].w * inv[rr]);
        st4(&out[(size_t)(b * T_ + r0 + tr * 4 + rr) * NU_ + h * DH_ + tc * 4], o);
    }
    if (t < 64) rsws[(size_t)bh * T_ + r0 + t] = rs[t];
}

// ---------------------------------------------------------------------------
// Kernel 3 (phase 1): recompute scores (cheaper than a 537MB HBM round-trip),
// scale by 1/rowsum, write the normalized weights tensor; float4 zero-fill
// above the causal diagonal. Every element written exactly once per call.
// ---------------------------------------------------------------------------
__global__ __launch_bounds__(256) void attn_phase1_kernel(
    const float* __restrict__ qws, const float* __restrict__ kws,
    const float* __restrict__ rsws, float* __restrict__ wts)
{
    const int tile = blockIdx.x;
    const int bh   = blockIdx.y;
    const int b = bh >> 4, h = bh & 15;
    const int r0 = tile * 64;
    const int t  = threadIdx.x;
    const int tr = t >> 4, tc = t & 15;

    __shared__ float Qs[64][68];
    __shared__ float Ks[64][68];

    {
        const int row = t >> 2, c16 = (t & 3) * 16;
        const float* src = &qws[(size_t)(b * T_ + r0 + row) * NU_ + h * DH_ + c16];
        st4(&Qs[row][c16 + 0],  ld4(src + 0));
        st4(&Qs[row][c16 + 4],  ld4(src + 4));
        st4(&Qs[row][c16 + 8],  ld4(src + 8));
        st4(&Qs[row][c16 + 12], ld4(src + 12));
    }
    float inv[4];
#pragma unroll
    for (int rr = 0; rr < 4; ++rr)
        inv[rr] = 1.f / rsws[(size_t)bh * T_ + r0 + tr * 4 + rr];
    __syncthreads();

    for (int ch = 0; ch < T_ / 64; ++ch) {
        const int jc = ch * 64;
        if (ch <= tile) {   // block-uniform branch
            {
                const int row = t >> 2, c16 = (t & 3) * 16;
                const float* src = &kws[(size_t)(b * T_ + jc + row) * NU_ + h * DH_ + c16];
                st4(&Ks[row][c16 + 0],  ld4(src + 0));
                st4(&Ks[row][c16 + 4],  ld4(src + 4));
                st4(&Ks[row][c16 + 8],  ld4(src + 8));
                st4(&Ks[row][c16 + 12], ld4(src + 12));
            }
            __syncthreads();

            float s[4][4];
#pragma unroll
            for (int rr = 0; rr < 4; ++rr)
#pragma unroll
                for (int c = 0; c < 4; ++c) s[rr][c] = 0.f;

#pragma unroll
            for (int d4 = 0; d4 < 16; ++d4) {
                float4 q[4], kf[4];
#pragma unroll
                for (int rr = 0; rr < 4; ++rr) q[rr] = ld4(&Qs[tr * 4 + rr][d4 * 4]);
#pragma unroll
                for (int c = 0; c < 4; ++c) kf[c] = ld4(&Ks[tc + c * 16][d4 * 4]);
#pragma unroll
                for (int rr = 0; rr < 4; ++rr)
#pragma unroll
                    for (int c = 0; c < 4; ++c) {
                        s[rr][c] = fmaf(q[rr].x, kf[c].x, s[rr][c]);
                        s[rr][c] = fmaf(q[rr].y, kf[c].y, s[rr][c]);
                        s[rr][c] = fmaf(q[rr].z, kf[c].z, s[rr][c]);
                        s[rr][c] = fmaf(q[rr].w, kf[c].w, s[rr][c]);
                    }
            }

#pragma unroll
            for (int rr = 0; rr < 4; ++rr) {
                const int i = r0 + tr * 4 + rr;
                const size_t rowbase = ((size_t)bh * T_ + i) * T_;
#pragma unroll
                for (int c = 0; c < 4; ++c) {
                    const int j = jc + tc + c * 16;
                    const float w = (j <= i) ? __expf(s[rr][c] * SCALE) * inv[rr] : 0.f;
                    wts[rowbase + j] = w;
                }
            }
            __syncthreads();   // K reads done before next stage
        } else {
            // fully above the diagonal: vectorized zero fill
            const int row = t >> 2, c16 = (t & 3) * 16;
            float* dst = &wts[((size_t)bh * T_ + r0 + row) * T_ + jc + c16];
            const float4 z = make_float4(0.f, 0.f, 0.f, 0.f);
            st4(dst + 0, z); st4(dst + 4, z); st4(dst + 8, z); st4(dst + 12, z);
        }
    }
}

// ---------------------------------------------------------------------------
extern "C" void kernel_launch(void* const* d_in, const int* in_sizes, int n_in,
                              void* d_out, int out_size, void* d_ws, size_t ws_size,
                              hipStream_t stream)
{
    const float* queries = (const float*)d_in[0];
    const float* keys    = (const float*)d_in[1];
    const float* Wq = (const float*)d_in[2];
    const float* bq = (const float*)d_in[3];
    const float* Wk = (const float*)d_in[4];
    const float* bk = (const float*)d_in[5];
    const float* Wv = (const float*)d_in[6];
    const float* bv = (const float*)d_in[7];

    float* out = (float*)d_out;                 // [B,T,NU]
    float* wts = out + OUT_ELEMS;               // [B,H,T,T]

    // workspace: q,k,v (fp32, B*T*NU each) + rowsums (B*H*T) = ~48.3 MB
    float* qws  = (float*)d_ws;
    float* kws  = qws + (size_t)B_ * T_ * NU_;
    float* vws  = kws + (size_t)B_ * T_ * NU_;
    float* rsws = vws + (size_t)B_ * T_ * NU_;

    proj_gemm_kernel<<<dim3(NU_ / 128, (B_ * T_) / 128, 3), 256, 0, stream>>>(
        queries, keys, Wq, bq, Wk, bk, Wv, bv, qws, kws, vws);
    attn_phase0_kernel<<<dim3(T_ / 64, B_ * H_), 256, 0, stream>>>(
        qws, kws, vws, rsws, out);
    attn_phase1_kernel<<<dim3(T_ / 64, B_ * H_), 256, 0, stream>>>(
        qws, kws, rsws, wts);
}

// Round 2
// 539.894 us; speedup vs baseline: 3.8987x; 3.8987x over previous
//
#include <hip/hip_runtime.h>
#include <cstddef>
#include <cstdint>

// Problem constants (reference: B=2, T=2048, D=1024, H=16, DH=64, NU=1024)
namespace {
constexpr int B_ = 2, T_ = 2048, D_ = 1024, H_ = 16, DH_ = 64, NU_ = 1024;
constexpr float SCALE = 0.03125f;           // NU^-0.5 = 1/32
constexpr size_t OUT_ELEMS = (size_t)B_ * T_ * NU_;   // 4,194,304
}

using f4  = __attribute__((ext_vector_type(4))) float;
using s8v = __attribute__((ext_vector_type(8))) short;   // 8 bf16 (4 VGPRs)
using s4v = __attribute__((ext_vector_type(4))) short;

#define MFMA16(a, b, c) __builtin_amdgcn_mfma_f32_16x16x32_bf16((a), (b), (c), 0, 0, 0)

__device__ __forceinline__ float4 ld4(const float* p) { return *reinterpret_cast<const float4*>(p); }
__device__ __forceinline__ void st4(float* p, const float4 v) { *reinterpret_cast<float4*>(p) = v; }
__device__ __forceinline__ short f2bf(float f) {      // fp32 -> bf16 RNE
    union { float f; uint32_t u; } v{f};
    uint32_t r = (v.u + 0x7fffu + ((v.u >> 16) & 1u)) >> 16;
    return (short)r;
}

// ---------------------------------------------------------------------------
// Convert queries/keys fp32 -> bf16 row-major. grid (N/2048, 2).
// ---------------------------------------------------------------------------
__global__ __launch_bounds__(256) void cvt_x_kernel(
    const float* __restrict__ q, const float* __restrict__ k,
    short* __restrict__ qx, short* __restrict__ kx)
{
    const float* src = blockIdx.y ? k : q;
    short* dst       = blockIdx.y ? kx : qx;
    size_t i = ((size_t)blockIdx.x * 256 + threadIdx.x) * 8;
    float4 a = ld4(src + i), b = ld4(src + i + 4);
    s8v o = { f2bf(a.x), f2bf(a.y), f2bf(a.z), f2bf(a.w),
              f2bf(b.x), f2bf(b.y), f2bf(b.z), f2bf(b.w) };
    *reinterpret_cast<s8v*>(dst + i) = o;
}

// ---------------------------------------------------------------------------
// Convert + transpose W fp32 [K][N] -> bf16 Wt [N][K]. grid (16,16,3).
// LDS 64x64 tile, padded stride 68 (conflict-free column reads).
// ---------------------------------------------------------------------------
__global__ __launch_bounds__(256) void cvt_w_kernel(
    const float* __restrict__ Wq, const float* __restrict__ Wk,
    const float* __restrict__ Wv, short* __restrict__ wt3)
{
    const int z = blockIdx.z;
    const float* W = (z == 0) ? Wq : (z == 1) ? Wk : Wv;
    short* dst = wt3 + (size_t)z * D_ * NU_;
    const int n0 = blockIdx.x * 64, k0 = blockIdx.y * 64;
    __shared__ float tl[64][68];
    const int rr = threadIdx.x >> 2, cc = (threadIdx.x & 3) * 16;
    const float* s = W + (size_t)(k0 + rr) * NU_ + n0 + cc;
    st4(&tl[rr][cc + 0],  ld4(s + 0));
    st4(&tl[rr][cc + 4],  ld4(s + 4));
    st4(&tl[rr][cc + 8],  ld4(s + 8));
    st4(&tl[rr][cc + 12], ld4(s + 12));
    __syncthreads();
    short* d = dst + (size_t)(n0 + rr) * D_ + k0 + cc;
#pragma unroll
    for (int c = 0; c < 4; ++c) {
        s4v o = { f2bf(tl[cc + c * 4 + 0][rr]), f2bf(tl[cc + c * 4 + 1][rr]),
                  f2bf(tl[cc + c * 4 + 2][rr]), f2bf(tl[cc + c * 4 + 3][rr]) };
        *reinterpret_cast<s4v*>(d + c * 4) = o;
    }
}

// ---------------------------------------------------------------------------
// QKV projection, bf16 MFMA. Y = X @ W + bias. X bf16 [4096][1024], Wt bf16
// [N][K] (pre-transposed). 128x128 tile, BK=32, 4 waves (2x2), 64x64/wave,
// 16x16x32 mfma, reg-staged LDS. z=0 -> qb, z=1 -> kb, z=2 -> vt (V stored
// transposed per head: [b*16+h][d][t], so PV B-frags are contiguous).
// grid (8, 32, 3), 256 threads.
// ---------------------------------------------------------------------------
__global__ __launch_bounds__(256) void proj_mfma(
    const short* __restrict__ qx, const short* __restrict__ kx,
    const short* __restrict__ wt3,
    const float* __restrict__ bq, const float* __restrict__ bk,
    const float* __restrict__ bv,
    short* __restrict__ qb, short* __restrict__ kb, short* __restrict__ vt)
{
    const int z = blockIdx.z;
    const short* __restrict__ X  = (z == 0) ? qx : kx;
    const short* __restrict__ Wt = wt3 + (size_t)z * D_ * NU_;
    const float* __restrict__ bias = (z == 0) ? bq : (z == 1) ? bk : bv;

    const int n0 = blockIdx.x * 128, m0 = blockIdx.y * 128;
    const int t = threadIdx.x, w = t >> 6, l = t & 63;
    const int lr = l & 15, lg = l >> 4;
    const int wr = w >> 1, wc = w & 1;

    __shared__ short Asl[128 * 32];   // [row][k] linear
    __shared__ short Bsl[128 * 32];   // [n][k] linear

    f4 acc[4][4];
#pragma unroll
    for (int m = 0; m < 4; ++m)
#pragma unroll
        for (int n = 0; n < 4; ++n) acc[m][n] = (f4){0.f, 0.f, 0.f, 0.f};

    const int sr = t >> 1, sc = (t & 1) * 16;     // staging: row, col-half
    const short* ga = X  + (size_t)(m0 + sr) * D_ + sc;
    const short* gb = Wt + (size_t)(n0 + sr) * D_ + sc;
    short* la = &Asl[sr * 32 + sc];
    short* lb = &Bsl[sr * 32 + sc];

    for (int k0 = 0; k0 < D_; k0 += 32) {
        s8v a0 = *reinterpret_cast<const s8v*>(ga + k0);
        s8v a1 = *reinterpret_cast<const s8v*>(ga + k0 + 8);
        s8v b0 = *reinterpret_cast<const s8v*>(gb + k0);
        s8v b1 = *reinterpret_cast<const s8v*>(gb + k0 + 8);
        __syncthreads();   // prior reads done before overwrite
        *reinterpret_cast<s8v*>(la)     = a0;
        *reinterpret_cast<s8v*>(la + 8) = a1;
        *reinterpret_cast<s8v*>(lb)     = b0;
        *reinterpret_cast<s8v*>(lb + 8) = b1;
        __syncthreads();

        s8v af[4], bf[4];
#pragma unroll
        for (int m = 0; m < 4; ++m)
            af[m] = *reinterpret_cast<const s8v*>(&Asl[(wr * 64 + m * 16 + lr) * 32 + lg * 8]);
#pragma unroll
        for (int n = 0; n < 4; ++n)
            bf[n] = *reinterpret_cast<const s8v*>(&Bsl[(wc * 64 + n * 16 + lr) * 32 + lg * 8]);
#pragma unroll
        for (int m = 0; m < 4; ++m)
#pragma unroll
            for (int n = 0; n < 4; ++n)
                acc[m][n] = MFMA16(af[m], bf[n], acc[m][n]);
    }

    // epilogue: C/D layout col=lane&15, row=(lane>>4)*4+reg  [m89-verified]
    if (z < 2) {
        short* __restrict__ Y = (z == 0) ? qb : kb;
#pragma unroll
        for (int n = 0; n < 4; ++n) {
            const int col = n0 + wc * 64 + n * 16 + lr;
            const float bval = bias[col];
#pragma unroll
            for (int m = 0; m < 4; ++m) {
                const int row0 = m0 + wr * 64 + m * 16 + lg * 4;
#pragma unroll
                for (int r = 0; r < 4; ++r)
                    Y[(size_t)(row0 + r) * NU_ + col] = f2bf(acc[m][n][r] + bval);
            }
        }
    } else {
#pragma unroll
        for (int n = 0; n < 4; ++n) {
            const int col = n0 + wc * 64 + n * 16 + lr;   // 0..1023
            const float bval = bias[col];
            const int hh = col >> 6, dd = col & 63;
#pragma unroll
            for (int m = 0; m < 4; ++m) {
                const int Mi = m0 + wr * 64 + m * 16 + lg * 4;
                const int bb = Mi >> 11, t0 = Mi & 2047;
                s4v o = { f2bf(acc[m][n][0] + bval), f2bf(acc[m][n][1] + bval),
                          f2bf(acc[m][n][2] + bval), f2bf(acc[m][n][3] + bval) };
                *reinterpret_cast<s4v*>(vt + ((size_t)(bb * 16 + hh) * 64 + dd) * T_ + t0) = o;
            }
        }
    }
}

// ---------------------------------------------------------------------------
// Phase 0: flash-style pass. 4 independent waves x 16 q-rows; Q/K/V frags
// straight from global (K/V L2-resident); P via per-wave XOR-swizzled LDS
// (fixes the C/D->A-frag transpose); rowsums in-register via shfl_xor.
// No barriers (per-wave-private LDS; DS ops in-order within a wave).
// grid (32, 32) with heavy tiles first, 256 threads.
// ---------------------------------------------------------------------------
__global__ __launch_bounds__(256) void attn_phase0_mfma(
    const short* __restrict__ qb, const short* __restrict__ kb,
    const short* __restrict__ vt, float* __restrict__ rsws,
    float* __restrict__ out)
{
    const int tile = gridDim.x - 1 - blockIdx.x;   // heavy tiles launch first
    const int bh = blockIdx.y;
    const int b = bh >> 4, h = bh & 15;
    const int r0 = tile * 64;
    const int t = threadIdx.x, w = t >> 6, l = t & 63;
    const int lr = l & 15, lg = l >> 4;

    __shared__ short Pl[4 * 1024];     // per-wave 16x64 bf16, swizzled

    // Q fragments (A: row=lane&15, k=(lane>>4)*8+e)
    const short* qrow = qb + (size_t)(b * T_ + r0 + w * 16 + lr) * NU_ + h * DH_ + lg * 8;
    const s8v qf0 = *reinterpret_cast<const s8v*>(qrow);
    const s8v qf1 = *reinterpret_cast<const s8v*>(qrow + 32);

    f4 accO[4];
#pragma unroll
    for (int nt = 0; nt < 4; ++nt) accO[nt] = (f4){0.f, 0.f, 0.f, 0.f};
    float rsum[4] = {0.f, 0.f, 0.f, 0.f};
    const f4 zf = (f4){0.f, 0.f, 0.f, 0.f};

    for (int ch = 0; ch <= tile; ++ch) {
        const int jc = ch * 64;
        const bool diag = (ch == tile);

        // ---- QK^T: S[16][64] as 4 n-tiles ----
        f4 s[4];
        const short* kbase = kb + (size_t)(b * T_ + jc) * NU_ + h * DH_ + lg * 8;
#pragma unroll
        for (int nt = 0; nt < 4; ++nt) {
            const short* kr = kbase + (size_t)(nt * 16 + lr) * NU_;
            s8v kf0 = *reinterpret_cast<const s8v*>(kr);
            s8v kf1 = *reinterpret_cast<const s8v*>(kr + 32);
            f4 a = MFMA16(qf0, kf0, zf);
            s[nt] = MFMA16(qf1, kf1, a);
        }

        // ---- exp + mask; write P (bf16, swizzled); partial row-sums ----
        float ps[4] = {0.f, 0.f, 0.f, 0.f};
#pragma unroll
        for (int nt = 0; nt < 4; ++nt) {
#pragma unroll
            for (int r = 0; r < 4; ++r) {
                const int row = lg * 4 + r;          // local q-row 0..15
                const int col = nt * 16 + lr;        // local j 0..63
                float e = __expf(s[nt][r] * SCALE);
                if (diag && (col > w * 16 + row)) e = 0.f;
                ps[r] += e;
                Pl[w * 1024 + row * 64 + (col ^ ((row & 7) << 3))] = f2bf(e);
            }
        }
#pragma unroll
        for (int r = 0; r < 4; ++r) {                // reduce over lane&15
            ps[r] += __shfl_xor(ps[r], 1);
            ps[r] += __shfl_xor(ps[r], 2);
            ps[r] += __shfl_xor(ps[r], 4);
            ps[r] += __shfl_xor(ps[r], 8);
            rsum[r] += ps[r];
        }

        // ---- PV: A=P (from LDS, swizzled b128), B=V^T rows (global 16B) ----
        s8v pf0 = *reinterpret_cast<const s8v*>(
            &Pl[w * 1024 + lr * 64 + ((lg * 8) ^ ((lr & 7) << 3))]);
        s8v pf1 = *reinterpret_cast<const s8v*>(
            &Pl[w * 1024 + lr * 64 + (((4 + lg) * 8) ^ ((lr & 7) << 3))]);
#pragma unroll
        for (int nt = 0; nt < 4; ++nt) {
            const short* vr = vt + (size_t)(bh * 64 + nt * 16 + lr) * T_ + jc + lg * 8;
            s8v vf0 = *reinterpret_cast<const s8v*>(vr);
            s8v vf1 = *reinterpret_cast<const s8v*>(vr + 32);
            accO[nt] = MFMA16(pf0, vf0, accO[nt]);
            accO[nt] = MFMA16(pf1, vf1, accO[nt]);
        }
    }

    // ---- finalize ----
    float inv[4];
#pragma unroll
    for (int r = 0; r < 4; ++r) inv[r] = 1.f / rsum[r];
#pragma unroll
    for (int nt = 0; nt < 4; ++nt)
#pragma unroll
        for (int r = 0; r < 4; ++r)
            out[(size_t)(b * T_ + r0 + w * 16 + lg * 4 + r) * NU_ + h * DH_ + nt * 16 + lr] =
                accO[nt][r] * inv[r];
    if (lr == 0)
#pragma unroll
        for (int r = 0; r < 4; ++r)
            rsws[(size_t)bh * T_ + r0 + w * 16 + lg * 4 + r] = rsum[r];
}

// ---------------------------------------------------------------------------
// Phase 1: MFMA score recompute -> normalized weights write; float4 zero-fill
// above the diagonal. No LDS, no barriers. grid (32, 32), 256 threads.
// ---------------------------------------------------------------------------
__global__ __launch_bounds__(256) void attn_phase1_mfma(
    const short* __restrict__ qb, const short* __restrict__ kb,
    const float* __restrict__ rsws, float* __restrict__ wts)
{
    const int tile = gridDim.x - 1 - blockIdx.x;
    const int bh = blockIdx.y;
    const int b = bh >> 4, h = bh & 15;
    const int r0 = tile * 64;
    const int t = threadIdx.x, w = t >> 6, l = t & 63;
    const int lr = l & 15, lg = l >> 4;

    const short* qrow = qb + (size_t)(b * T_ + r0 + w * 16 + lr) * NU_ + h * DH_ + lg * 8;
    const s8v qf0 = *reinterpret_cast<const s8v*>(qrow);
    const s8v qf1 = *reinterpret_cast<const s8v*>(qrow + 32);
    const f4 zf = (f4){0.f, 0.f, 0.f, 0.f};

    float inv[4];
#pragma unroll
    for (int r = 0; r < 4; ++r)
        inv[r] = 1.f / rsws[(size_t)bh * T_ + r0 + w * 16 + lg * 4 + r];

    for (int ch = 0; ch < T_ / 64; ++ch) {
        const int jc = ch * 64;
        if (ch <= tile) {
            const bool diag = (ch == tile);
            f4 s[4];
            const short* kbase = kb + (size_t)(b * T_ + jc) * NU_ + h * DH_ + lg * 8;
#pragma unroll
            for (int nt = 0; nt < 4; ++nt) {
                const short* kr = kbase + (size_t)(nt * 16 + lr) * NU_;
                s8v kf0 = *reinterpret_cast<const s8v*>(kr);
                s8v kf1 = *reinterpret_cast<const s8v*>(kr + 32);
                f4 a = MFMA16(qf0, kf0, zf);
                s[nt] = MFMA16(qf1, kf1, a);
            }
#pragma unroll
            for (int nt = 0; nt < 4; ++nt) {
#pragma unroll
                for (int r = 0; r < 4; ++r) {
                    const int il = w * 16 + lg * 4 + r;    // local i 0..63
                    const int jl = nt * 16 + lr;           // local j 0..63
                    float e = __expf(s[nt][r] * SCALE) * inv[r];
                    if (diag && (jl > il)) e = 0.f;
                    wts[((size_t)bh * T_ + r0 + il) * T_ + jc + jl] = e;
                }
            }
        } else {
            float* dst = &wts[((size_t)bh * T_ + r0 + (t >> 2)) * T_ + jc + (t & 3) * 16];
            const float4 z4 = make_float4(0.f, 0.f, 0.f, 0.f);
            st4(dst + 0, z4); st4(dst + 4, z4); st4(dst + 8, z4); st4(dst + 12, z4);
        }
    }
}

// ---------------------------------------------------------------------------
extern "C" void kernel_launch(void* const* d_in, const int* in_sizes, int n_in,
                              void* d_out, int out_size, void* d_ws, size_t ws_size,
                              hipStream_t stream)
{
    const float* queries = (const float*)d_in[0];
    const float* keys    = (const float*)d_in[1];
    const float* Wq = (const float*)d_in[2];
    const float* bq = (const float*)d_in[3];
    const float* Wk = (const float*)d_in[4];
    const float* bk = (const float*)d_in[5];
    const float* Wv = (const float*)d_in[6];
    const float* bv = (const float*)d_in[7];

    float* out = (float*)d_out;                 // [B,T,NU]
    float* wts = out + OUT_ELEMS;               // [B,H,T,T]

    // workspace (bf16 shorts unless noted), total ~48.5 MB:
    short* qx = (short*)d_ws;                               // queries bf16 [4096][1024]
    short* kx = qx + (size_t)B_ * T_ * D_;                  // keys bf16
    short* wt = kx + (size_t)B_ * T_ * D_;                  // Wt bf16 [3][N][K]
    short* qb = wt + (size_t)3 * D_ * NU_;                  // q proj bf16 [4096][1024]
    short* kb = qb + (size_t)B_ * T_ * NU_;                 // k proj bf16
    short* vt = kb + (size_t)B_ * T_ * NU_;                 // v proj bf16, [bh][d][t]
    float* rsws = (float*)(vt + (size_t)B_ * T_ * NU_);     // rowsums [bh][t]

    cvt_x_kernel<<<dim3((B_ * T_ * D_) / 2048, 2), 256, 0, stream>>>(queries, keys, qx, kx);
    cvt_w_kernel<<<dim3(16, 16, 3), 256, 0, stream>>>(Wq, Wk, Wv, wt);
    proj_mfma<<<dim3(NU_ / 128, (B_ * T_) / 128, 3), 256, 0, stream>>>(
        qx, kx, wt, bq, bk, bv, qb, kb, vt);
    attn_phase0_mfma<<<dim3(T_ / 64, B_ * H_), 256, 0, stream>>>(qb, kb, vt, rsws, out);
    attn_phase1_mfma<<<dim3(T_ / 64, B_ * H_), 256, 0, stream>>>(qb, kb, rsws, wts);
}

// Round 3
// 508.585 us; speedup vs baseline: 4.1387x; 1.0616x over previous
//
#include <hip/hip_runtime.h>
#include <cstddef>
#include <cstdint>

// Problem constants (reference: B=2, T=2048, D=1024, H=16, DH=64, NU=1024)
namespace {
constexpr int B_ = 2, T_ = 2048, D_ = 1024, H_ = 16, DH_ = 64, NU_ = 1024;
constexpr float SCALE = 0.03125f;           // NU^-0.5 = 1/32
constexpr size_t OUT_ELEMS = (size_t)B_ * T_ * NU_;   // 4,194,304
}

using f4  = __attribute__((ext_vector_type(4))) float;
using s8v = __attribute__((ext_vector_type(8))) short;   // 8 bf16 (4 VGPRs)
using s4v = __attribute__((ext_vector_type(4))) short;

#define MFMA16(a, b, c) __builtin_amdgcn_mfma_f32_16x16x32_bf16((a), (b), (c), 0, 0, 0)

__device__ __forceinline__ float4 ld4(const float* p) { return *reinterpret_cast<const float4*>(p); }
__device__ __forceinline__ void st4(float* p, const float4 v) { *reinterpret_cast<float4*>(p) = v; }
__device__ __forceinline__ short f2bf(float f) {      // fp32 -> bf16 RNE
    union { float f; uint32_t u; } v{f};
    uint32_t r = (v.u + 0x7fffu + ((v.u >> 16) & 1u)) >> 16;
    return (short)r;
}

#if __has_builtin(__builtin_amdgcn_global_load_lds)
#define HAVE_GLOAD_LDS 1
__device__ __forceinline__ void load_lds16(const void* g, void* l) {
    __builtin_amdgcn_global_load_lds(
        (const __attribute__((address_space(1))) void*)g,
        (__attribute__((address_space(3))) void*)l, 16, 0, 0);
}
#else
#define HAVE_GLOAD_LDS 0
#endif

// ---------------------------------------------------------------------------
// Convert queries/keys fp32 -> bf16 row-major. grid (N/2048, 2).
// ---------------------------------------------------------------------------
__global__ __launch_bounds__(256) void cvt_x_kernel(
    const float* __restrict__ q, const float* __restrict__ k,
    short* __restrict__ qx, short* __restrict__ kx)
{
    const float* src = blockIdx.y ? k : q;
    short* dst       = blockIdx.y ? kx : qx;
    size_t i = ((size_t)blockIdx.x * 256 + threadIdx.x) * 8;
    float4 a = ld4(src + i), b = ld4(src + i + 4);
    s8v o = { f2bf(a.x), f2bf(a.y), f2bf(a.z), f2bf(a.w),
              f2bf(b.x), f2bf(b.y), f2bf(b.z), f2bf(b.w) };
    *reinterpret_cast<s8v*>(dst + i) = o;
}

// ---------------------------------------------------------------------------
// Convert + transpose W fp32 [K][N] -> bf16 Wt [N][K]. grid (16,16,3).
// ---------------------------------------------------------------------------
__global__ __launch_bounds__(256) void cvt_w_kernel(
    const float* __restrict__ Wq, const float* __restrict__ Wk,
    const float* __restrict__ Wv, short* __restrict__ wt3)
{
    const int z = blockIdx.z;
    const float* W = (z == 0) ? Wq : (z == 1) ? Wk : Wv;
    short* dst = wt3 + (size_t)z * D_ * NU_;
    const int n0 = blockIdx.x * 64, k0 = blockIdx.y * 64;
    __shared__ float tl[64][68];
    const int rr = threadIdx.x >> 2, cc = (threadIdx.x & 3) * 16;
    const float* s = W + (size_t)(k0 + rr) * NU_ + n0 + cc;
    st4(&tl[rr][cc + 0],  ld4(s + 0));
    st4(&tl[rr][cc + 4],  ld4(s + 4));
    st4(&tl[rr][cc + 8],  ld4(s + 8));
    st4(&tl[rr][cc + 12], ld4(s + 12));
    __syncthreads();
    short* d = dst + (size_t)(n0 + rr) * D_ + k0 + cc;
#pragma unroll
    for (int c = 0; c < 4; ++c) {
        s4v o = { f2bf(tl[cc + c * 4 + 0][rr]), f2bf(tl[cc + c * 4 + 1][rr]),
                  f2bf(tl[cc + c * 4 + 2][rr]), f2bf(tl[cc + c * 4 + 3][rr]) };
        *reinterpret_cast<s4v*>(d + c * 4) = o;
    }
}

// ---------------------------------------------------------------------------
// QKV projection, bf16 MFMA, m97 structure: 128x128 tile, BK=32, 4 waves,
// global_load_lds width-16 staging into linear [128][32] LDS, 8 ds_read_b128
// + 16 MFMA per K-step. z=0->qb, z=1->kb, z=2->vt ([bh][d][t] transposed).
// grid (8, 32, 3), 256 threads.
// ---------------------------------------------------------------------------
__global__ __launch_bounds__(256) void proj_mfma(
    const short* __restrict__ qx, const short* __restrict__ kx,
    const short* __restrict__ wt3,
    const float* __restrict__ bq, const float* __restrict__ bk,
    const float* __restrict__ bv,
    short* __restrict__ qb, short* __restrict__ kb, short* __restrict__ vt)
{
    const int z = blockIdx.z;
    const short* __restrict__ X  = (z == 0) ? qx : kx;
    const short* __restrict__ Wt = wt3 + (size_t)z * D_ * NU_;
    const float* __restrict__ bias = (z == 0) ? bq : (z == 1) ? bk : bv;

    const int n0 = blockIdx.x * 128, m0 = blockIdx.y * 128;
    const int t = threadIdx.x, w = t >> 6, l = t & 63;
    const int lr = l & 15, lg = l >> 4;
    const int wr = w >> 1, wc = w & 1;

    __shared__ short Asl[128 * 32];   // [row][k] linear, 8KB
    __shared__ short Bsl[128 * 32];   // [n][k] linear, 8KB

    f4 acc[4][4];
#pragma unroll
    for (int m = 0; m < 4; ++m)
#pragma unroll
        for (int n = 0; n < 4; ++n) acc[m][n] = (f4){0.f, 0.f, 0.f, 0.f};

#if !HAVE_GLOAD_LDS
    const int sr = t >> 1, sc = (t & 1) * 16;
#endif

    for (int k0 = 0; k0 < D_; k0 += 32) {
#if HAVE_GLOAD_LDS
        // stage: 512 16B-chunks per tile; chunk c -> row c>>2, col (c&3)*8.
        // each wave issues 2 insts per operand (wave-uniform LDS base).
#pragma unroll
        for (int j = 0; j < 2; ++j) {
            const int c0 = (w * 2 + j) * 64;
            const int c  = c0 + l;
            const int row = c >> 2, qo = (c & 3) * 8;
            load_lds16(X  + (size_t)(m0 + row) * D_ + k0 + qo, (char*)Asl + (size_t)c0 * 16);
            load_lds16(Wt + (size_t)(n0 + row) * D_ + k0 + qo, (char*)Bsl + (size_t)c0 * 16);
        }
        __syncthreads();   // drains vmcnt before any wave reads LDS
#else
        s8v a0 = *reinterpret_cast<const s8v*>(X  + (size_t)(m0 + sr) * D_ + k0 + sc);
        s8v a1 = *reinterpret_cast<const s8v*>(X  + (size_t)(m0 + sr) * D_ + k0 + sc + 8);
        s8v b0 = *reinterpret_cast<const s8v*>(Wt + (size_t)(n0 + sr) * D_ + k0 + sc);
        s8v b1 = *reinterpret_cast<const s8v*>(Wt + (size_t)(n0 + sr) * D_ + k0 + sc + 8);
        __syncthreads();
        *reinterpret_cast<s8v*>(&Asl[sr * 32 + sc])     = a0;
        *reinterpret_cast<s8v*>(&Asl[sr * 32 + sc + 8]) = a1;
        *reinterpret_cast<s8v*>(&Bsl[sr * 32 + sc])     = b0;
        *reinterpret_cast<s8v*>(&Bsl[sr * 32 + sc + 8]) = b1;
        __syncthreads();
#endif

        s8v af[4], bf[4];
#pragma unroll
        for (int m = 0; m < 4; ++m)
            af[m] = *reinterpret_cast<const s8v*>(&Asl[(wr * 64 + m * 16 + lr) * 32 + lg * 8]);
#pragma unroll
        for (int n = 0; n < 4; ++n)
            bf[n] = *reinterpret_cast<const s8v*>(&Bsl[(wc * 64 + n * 16 + lr) * 32 + lg * 8]);
#pragma unroll
        for (int m = 0; m < 4; ++m)
#pragma unroll
            for (int n = 0; n < 4; ++n)
                acc[m][n] = MFMA16(af[m], bf[n], acc[m][n]);
        __syncthreads();   // all reads done before next stage overwrites
    }

    // epilogue: C/D layout col=lane&15, row=(lane>>4)*4+reg  [m89-verified]
    if (z < 2) {
        short* __restrict__ Y = (z == 0) ? qb : kb;
#pragma unroll
        for (int n = 0; n < 4; ++n) {
            const int col = n0 + wc * 64 + n * 16 + lr;
            const float bval = bias[col];
#pragma unroll
            for (int m = 0; m < 4; ++m) {
                const int row0 = m0 + wr * 64 + m * 16 + lg * 4;
#pragma unroll
                for (int r = 0; r < 4; ++r)
                    Y[(size_t)(row0 + r) * NU_ + col] = f2bf(acc[m][n][r] + bval);
            }
        }
    } else {
#pragma unroll
        for (int n = 0; n < 4; ++n) {
            const int col = n0 + wc * 64 + n * 16 + lr;   // 0..1023
            const float bval = bias[col];
            const int hh = col >> 6, dd = col & 63;
#pragma unroll
            for (int m = 0; m < 4; ++m) {
                const int Mi = m0 + wr * 64 + m * 16 + lg * 4;
                const int bb = Mi >> 11, t0 = Mi & 2047;
                s4v o = { f2bf(acc[m][n][0] + bval), f2bf(acc[m][n][1] + bval),
                          f2bf(acc[m][n][2] + bval), f2bf(acc[m][n][3] + bval) };
                *reinterpret_cast<s4v*>(vt + ((size_t)(bb * 16 + hh) * 64 + dd) * T_ + t0) = o;
            }
        }
    }
}

// ---------------------------------------------------------------------------
// Phase 0: flash pass with SWAPPED QK^T (mfma(K,Q)) so each lane holds 4
// consecutive j of one q-row: P-writes are 4x ds_write_b64 (XOR-swizzled,
// 2-way max), rowsum is in-lane (+2 shuffles at the end), zero per-chunk
// shuffles. PV unchanged (A=P from LDS b128, B=V^T rows 16B from global).
// No barriers (per-wave-private LDS). grid (32, 32) heavy-first, 256 thr.
// ---------------------------------------------------------------------------
__global__ __launch_bounds__(256) void attn_phase0_mfma(
    const short* __restrict__ qb, const short* __restrict__ kb,
    const short* __restrict__ vt, float* __restrict__ rsws,
    float* __restrict__ out)
{
    const int tile = gridDim.x - 1 - blockIdx.x;   // heavy tiles launch first
    const int bh = blockIdx.y;
    const int b = bh >> 4, h = bh & 15;
    const int r0 = tile * 64;
    const int t = threadIdx.x, w = t >> 6, l = t & 63;
    const int lr = l & 15, lg = l >> 4;

    __shared__ short Pl[4 * 1024];     // per-wave 16x64 bf16, swizzled

    // Q fragments (used as B-operand: col=lane&15=q-row, k=(lane>>4)*8+e=d)
    const short* qrow = qb + (size_t)(b * T_ + r0 + w * 16 + lr) * NU_ + h * DH_ + lg * 8;
    const s8v qf0 = *reinterpret_cast<const s8v*>(qrow);
    const s8v qf1 = *reinterpret_cast<const s8v*>(qrow + 32);

    f4 accO[4];
#pragma unroll
    for (int nt = 0; nt < 4; ++nt) accO[nt] = (f4){0.f, 0.f, 0.f, 0.f};
    float rsum = 0.f;
    const f4 zf = (f4){0.f, 0.f, 0.f, 0.f};
    const int sw = (lr & 7) << 3;      // P swizzle keyed on q-row (=lr)

    for (int ch = 0; ch <= tile; ++ch) {
        const int jc = ch * 64;
        const bool diag = (ch == tile);

        // ---- swapped QK^T: s[nt][r] = S[q = lr][j = nt*16 + lg*4 + r] ----
        f4 s[4];
        const short* kbase = kb + (size_t)(b * T_ + jc) * NU_ + h * DH_ + lg * 8;
#pragma unroll
        for (int nt = 0; nt < 4; ++nt) {
            const short* kr = kbase + (size_t)(nt * 16 + lr) * NU_;
            s8v kf0 = *reinterpret_cast<const s8v*>(kr);
            s8v kf1 = *reinterpret_cast<const s8v*>(kr + 32);
            f4 a = MFMA16(kf0, qf0, zf);
            s[nt] = MFMA16(kf1, qf1, a);
        }

        // ---- exp + mask; in-lane rowsum; pack 4 bf16 -> one b64 per nt ----
#pragma unroll
        for (int nt = 0; nt < 4; ++nt) {
            float e[4];
#pragma unroll
            for (int r = 0; r < 4; ++r) {
                float v = __expf(s[nt][r] * SCALE);
                if (diag && (nt * 16 + lg * 4 + r > w * 16 + lr)) v = 0.f;
                e[r] = v;
            }
            rsum += (e[0] + e[1]) + (e[2] + e[3]);
            const int colp = (nt * 16 + lg * 4) ^ sw;
            s4v pv = { f2bf(e[0]), f2bf(e[1]), f2bf(e[2]), f2bf(e[3]) };
            *reinterpret_cast<s4v*>(&Pl[w * 1024 + lr * 64 + colp]) = pv;
        }

        // ---- PV: A = P[q=lane&15][j], B = V^T rows (global, 16B) ----
        s8v pf0 = *reinterpret_cast<const s8v*>(&Pl[w * 1024 + lr * 64 + ((lg * 8) ^ sw)]);
        s8v pf1 = *reinterpret_cast<const s8v*>(&Pl[w * 1024 + lr * 64 + ((32 + lg * 8) ^ sw)]);
#pragma unroll
        for (int nt = 0; nt < 4; ++nt) {
            const short* vr = vt + (size_t)(bh * 64 + nt * 16 + lr) * T_ + jc + lg * 8;
            s8v vf0 = *reinterpret_cast<const s8v*>(vr);
            s8v vf1 = *reinterpret_cast<const s8v*>(vr + 32);
            accO[nt] = MFMA16(pf0, vf0, accO[nt]);
            accO[nt] = MFMA16(pf1, vf1, accO[nt]);
        }
    }

    // ---- reduce rowsums (disjoint partials live at lanes lr, lr+16, ...) ----
    rsum += __shfl_xor(rsum, 16);
    rsum += __shfl_xor(rsum, 32);      // now every lane: full sum for q=lr
    if (lg == 0)
        rsws[(size_t)bh * T_ + r0 + w * 16 + lr] = rsum;

    // redistribute: lane needs rows lg*4+r -> broadcast from lanes 0..15
    float inv[4];
#pragma unroll
    for (int r = 0; r < 4; ++r) inv[r] = 1.f / __shfl(rsum, lg * 4 + r);
#pragma unroll
    for (int nt = 0; nt < 4; ++nt)
#pragma unroll
        for (int r = 0; r < 4; ++r)
            out[(size_t)(b * T_ + r0 + w * 16 + lg * 4 + r) * NU_ + h * DH_ + nt * 16 + lr] =
                accO[nt][r] * inv[r];
}

// ---------------------------------------------------------------------------
// Phase 1: swapped-QK^T recompute -> each lane owns one q-row, 4 consecutive
// cols per nt -> 4x global_store_dwordx4 per chunk. inv is one scalar/lane.
// float4 zero-fill above the diagonal. grid (32, 32), 256 threads.
// ---------------------------------------------------------------------------
__global__ __launch_bounds__(256) void attn_phase1_mfma(
    const short* __restrict__ qb, const short* __restrict__ kb,
    const float* __restrict__ rsws, float* __restrict__ wts)
{
    const int tile = gridDim.x - 1 - blockIdx.x;
    const int bh = blockIdx.y;
    const int b = bh >> 4, h = bh & 15;
    const int r0 = tile * 64;
    const int t = threadIdx.x, w = t >> 6, l = t & 63;
    const int lr = l & 15, lg = l >> 4;

    const short* qrow = qb + (size_t)(b * T_ + r0 + w * 16 + lr) * NU_ + h * DH_ + lg * 8;
    const s8v qf0 = *reinterpret_cast<const s8v*>(qrow);
    const s8v qf1 = *reinterpret_cast<const s8v*>(qrow + 32);
    const f4 zf = (f4){0.f, 0.f, 0.f, 0.f};

    const int iRow = r0 + w * 16 + lr;                 // this lane's q-row
    const float inv = 1.f / rsws[(size_t)bh * T_ + iRow];
    float* const wrow = &wts[((size_t)bh * T_ + iRow) * T_];

    for (int ch = 0; ch < T_ / 64; ++ch) {
        const int jc = ch * 64;
        if (ch <= tile) {
            const bool diag = (ch == tile);
            f4 s[4];
            const short* kbase = kb + (size_t)(b * T_ + jc) * NU_ + h * DH_ + lg * 8;
#pragma unroll
            for (int nt = 0; nt < 4; ++nt) {
                const short* kr = kbase + (size_t)(nt * 16 + lr) * NU_;
                s8v kf0 = *reinterpret_cast<const s8v*>(kr);
                s8v kf1 = *reinterpret_cast<const s8v*>(kr + 32);
                f4 a = MFMA16(kf0, qf0, zf);
                s[nt] = MFMA16(kf1, qf1, a);
            }
#pragma unroll
            for (int nt = 0; nt < 4; ++nt) {
                float4 o;
                float* e = &o.x;
#pragma unroll
                for (int r = 0; r < 4; ++r) {
                    float v = __expf(s[nt][r] * SCALE) * inv;
                    if (diag && (nt * 16 + lg * 4 + r > w * 16 + lr)) v = 0.f;
                    e[r] = v;
                }
                st4(wrow + jc + nt * 16 + lg * 4, o);
            }
        } else {
            // fully above the diagonal: vectorized zero fill
            float* dst = &wts[((size_t)bh * T_ + r0 + (t >> 2)) * T_ + jc + (t & 3) * 16];
            const float4 z4 = make_float4(0.f, 0.f, 0.f, 0.f);
            st4(dst + 0, z4); st4(dst + 4, z4); st4(dst + 8, z4); st4(dst + 12, z4);
        }
    }
}

// ---------------------------------------------------------------------------
extern "C" void kernel_launch(void* const* d_in, const int* in_sizes, int n_in,
                              void* d_out, int out_size, void* d_ws, size_t ws_size,
                              hipStream_t stream)
{
    const float* queries = (const float*)d_in[0];
    const float* keys    = (const float*)d_in[1];
    const float* Wq = (const float*)d_in[2];
    const float* bq = (const float*)d_in[3];
    const float* Wk = (const float*)d_in[4];
    const float* bk = (const float*)d_in[5];
    const float* Wv = (const float*)d_in[6];
    const float* bv = (const float*)d_in[7];

    float* out = (float*)d_out;                 // [B,T,NU]
    float* wts = out + OUT_ELEMS;               // [B,H,T,T]

    // workspace (bf16 shorts unless noted), total ~48.5 MB:
    short* qx = (short*)d_ws;                               // queries bf16 [4096][1024]
    short* kx = qx + (size_t)B_ * T_ * D_;                  // keys bf16
    short* wt = kx + (size_t)B_ * T_ * D_;                  // Wt bf16 [3][N][K]
    short* qb = wt + (size_t)3 * D_ * NU_;                  // q proj bf16 [4096][1024]
    short* kb = qb + (size_t)B_ * T_ * NU_;                 // k proj bf16
    short* vt = kb + (size_t)B_ * T_ * NU_;                 // v proj bf16, [bh][d][t]
    float* rsws = (float*)(vt + (size_t)B_ * T_ * NU_);     // rowsums [bh][t]

    cvt_x_kernel<<<dim3((B_ * T_ * D_) / 2048, 2), 256, 0, stream>>>(queries, keys, qx, kx);
    cvt_w_kernel<<<dim3(16, 16, 3), 256, 0, stream>>>(Wq, Wk, Wv, wt);
    proj_mfma<<<dim3(NU_ / 128, (B_ * T_) / 128, 3), 256, 0, stream>>>(
        qx, kx, wt, bq, bk, bv, qb, kb, vt);
    attn_phase0_mfma<<<dim3(T_ / 64, B_ * H_), 256, 0, stream>>>(qb, kb, vt, rsws, out);
    attn_phase1_mfma<<<dim3(T_ / 64, B_ * H_), 256, 0, stream>>>(qb, kb, rsws, wts);
}

// Round 4
// 454.953 us; speedup vs baseline: 4.6266x; 1.1179x over previous
//
#include <hip/hip_runtime.h>
#include <cstddef>
#include <cstdint>

// Problem constants (reference: B=2, T=2048, D=1024, H=16, DH=64, NU=1024)
namespace {
constexpr int B_ = 2, T_ = 2048, D_ = 1024, H_ = 16, DH_ = 64, NU_ = 1024;
constexpr float SCALE = 0.03125f;           // NU^-0.5 = 1/32
constexpr size_t OUT_ELEMS = (size_t)B_ * T_ * NU_;   // 4,194,304
}

using f4  = __attribute__((ext_vector_type(4))) float;
using s8v = __attribute__((ext_vector_type(8))) short;   // 8 bf16 (4 VGPRs)
using s4v = __attribute__((ext_vector_type(4))) short;

#define MFMA16(a, b, c) __builtin_amdgcn_mfma_f32_16x16x32_bf16((a), (b), (c), 0, 0, 0)

__device__ __forceinline__ float4 ld4(const float* p) { return *reinterpret_cast<const float4*>(p); }
__device__ __forceinline__ void st4(float* p, const float4 v) { *reinterpret_cast<float4*>(p) = v; }
__device__ __forceinline__ short f2bf(float f) {      // fp32 -> bf16 RNE
    union { float f; uint32_t u; } v{f};
    uint32_t r = (v.u + 0x7fffu + ((v.u >> 16) & 1u)) >> 16;
    return (short)r;
}

#if __has_builtin(__builtin_amdgcn_global_load_lds)
#define HAVE_GLOAD_LDS 1
__device__ __forceinline__ void load_lds16(const void* g, void* l) {
    __builtin_amdgcn_global_load_lds(
        (const __attribute__((address_space(1))) void*)g,
        (__attribute__((address_space(3))) void*)l, 16, 0, 0);
}
#else
#define HAVE_GLOAD_LDS 0
#endif

// ---------------------------------------------------------------------------
// Convert queries/keys fp32 -> bf16 row-major. grid (N/2048, 2).
// ---------------------------------------------------------------------------
__global__ __launch_bounds__(256) void cvt_x_kernel(
    const float* __restrict__ q, const float* __restrict__ k,
    short* __restrict__ qx, short* __restrict__ kx)
{
    const float* src = blockIdx.y ? k : q;
    short* dst       = blockIdx.y ? kx : qx;
    size_t i = ((size_t)blockIdx.x * 256 + threadIdx.x) * 8;
    float4 a = ld4(src + i), b = ld4(src + i + 4);
    s8v o = { f2bf(a.x), f2bf(a.y), f2bf(a.z), f2bf(a.w),
              f2bf(b.x), f2bf(b.y), f2bf(b.z), f2bf(b.w) };
    *reinterpret_cast<s8v*>(dst + i) = o;
}

// ---------------------------------------------------------------------------
// Convert + transpose W fp32 [K][N] -> bf16 Wt [N][K]. grid (16,16,3).
// ---------------------------------------------------------------------------
__global__ __launch_bounds__(256) void cvt_w_kernel(
    const float* __restrict__ Wq, const float* __restrict__ Wk,
    const float* __restrict__ Wv, short* __restrict__ wt3)
{
    const int z = blockIdx.z;
    const float* W = (z == 0) ? Wq : (z == 1) ? Wk : Wv;
    short* dst = wt3 + (size_t)z * D_ * NU_;
    const int n0 = blockIdx.x * 64, k0 = blockIdx.y * 64;
    __shared__ float tl[64][68];
    const int rr = threadIdx.x >> 2, cc = (threadIdx.x & 3) * 16;
    const float* s = W + (size_t)(k0 + rr) * NU_ + n0 + cc;
    st4(&tl[rr][cc + 0],  ld4(s + 0));
    st4(&tl[rr][cc + 4],  ld4(s + 4));
    st4(&tl[rr][cc + 8],  ld4(s + 8));
    st4(&tl[rr][cc + 12], ld4(s + 12));
    __syncthreads();
    short* d = dst + (size_t)(n0 + rr) * D_ + k0 + cc;
#pragma unroll
    for (int c = 0; c < 4; ++c) {
        s4v o = { f2bf(tl[cc + c * 4 + 0][rr]), f2bf(tl[cc + c * 4 + 1][rr]),
                  f2bf(tl[cc + c * 4 + 2][rr]), f2bf(tl[cc + c * 4 + 3][rr]) };
        *reinterpret_cast<s4v*>(d + c * 4) = o;
    }
}

// ---------------------------------------------------------------------------
// QKV projection, bf16 MFMA: 128x128 tile, BK=64 (16 K-steps, halved barrier
// drains vs BK=32), 4 waves, global_load_lds width-16 into linear [128][64]
// LDS. XCD-chunked block remap (768 = 8 x 96) for A/B-panel L2 locality.
// z=0->qb, z=1->kb, z=2->vt ([bh][d][t] transposed). grid(8,32,3), 256 thr.
// ---------------------------------------------------------------------------
__global__ __launch_bounds__(256) void proj_mfma(
    const short* __restrict__ qx, const short* __restrict__ kx,
    const short* __restrict__ wt3,
    const float* __restrict__ bq, const float* __restrict__ bk,
    const float* __restrict__ bv,
    short* __restrict__ qb, short* __restrict__ kb, short* __restrict__ vt)
{
    // bijective XCD-chunked remap: lin%8 = XCD (HW round-robin assumption)
    const int lin = blockIdx.z * 256 + blockIdx.y * 8 + blockIdx.x;
    const int virt = (lin & 7) * 96 + (lin >> 3);
    const int z = virt >> 8, rem = virt & 255;
    const int m0 = (rem >> 3) * 128, n0 = (rem & 7) * 128;

    const short* __restrict__ X  = (z == 0) ? qx : kx;
    const short* __restrict__ Wt = wt3 + (size_t)z * D_ * NU_;
    const float* __restrict__ bias = (z == 0) ? bq : (z == 1) ? bk : bv;

    const int t = threadIdx.x, w = t >> 6, l = t & 63;
    const int lr = l & 15, lg = l >> 4;
    const int wr = w >> 1, wc = w & 1;

    __shared__ short Asl[128 * 64];   // [row][k] linear, 16KB
    __shared__ short Bsl[128 * 64];   // [n][k] linear, 16KB

    f4 acc[4][4];
#pragma unroll
    for (int m = 0; m < 4; ++m)
#pragma unroll
        for (int n = 0; n < 4; ++n) acc[m][n] = (f4){0.f, 0.f, 0.f, 0.f};

    for (int k0 = 0; k0 < D_; k0 += 64) {
#if HAVE_GLOAD_LDS
        // tile = 1024 16B-chunks; chunk c -> row c>>3, col (c&7)*8.
        // 4 insts/wave/operand, wave-uniform LDS base + lane*16.
#pragma unroll
        for (int j = 0; j < 4; ++j) {
            const int c0 = (w * 4 + j) * 64;
            const int c  = c0 + l;
            const int row = c >> 3, qo = (c & 7) * 8;
            load_lds16(X  + (size_t)(m0 + row) * D_ + k0 + qo, (char*)Asl + (size_t)c0 * 16);
            load_lds16(Wt + (size_t)(n0 + row) * D_ + k0 + qo, (char*)Bsl + (size_t)c0 * 16);
        }
        __syncthreads();   // drains vmcnt before any wave reads LDS
#else
        {
            const int sr = t >> 1, sc = (t & 1) * 32;
            s8v a0 = *reinterpret_cast<const s8v*>(X  + (size_t)(m0 + sr) * D_ + k0 + sc);
            s8v a1 = *reinterpret_cast<const s8v*>(X  + (size_t)(m0 + sr) * D_ + k0 + sc + 8);
            s8v a2 = *reinterpret_cast<const s8v*>(X  + (size_t)(m0 + sr) * D_ + k0 + sc + 16);
            s8v a3 = *reinterpret_cast<const s8v*>(X  + (size_t)(m0 + sr) * D_ + k0 + sc + 24);
            s8v b0 = *reinterpret_cast<const s8v*>(Wt + (size_t)(n0 + sr) * D_ + k0 + sc);
            s8v b1 = *reinterpret_cast<const s8v*>(Wt + (size_t)(n0 + sr) * D_ + k0 + sc + 8);
            s8v b2 = *reinterpret_cast<const s8v*>(Wt + (size_t)(n0 + sr) * D_ + k0 + sc + 16);
            s8v b3 = *reinterpret_cast<const s8v*>(Wt + (size_t)(n0 + sr) * D_ + k0 + sc + 24);
            __syncthreads();
            *reinterpret_cast<s8v*>(&Asl[sr * 64 + sc])      = a0;
            *reinterpret_cast<s8v*>(&Asl[sr * 64 + sc + 8])  = a1;
            *reinterpret_cast<s8v*>(&Asl[sr * 64 + sc + 16]) = a2;
            *reinterpret_cast<s8v*>(&Asl[sr * 64 + sc + 24]) = a3;
            *reinterpret_cast<s8v*>(&Bsl[sr * 64 + sc])      = b0;
            *reinterpret_cast<s8v*>(&Bsl[sr * 64 + sc + 8])  = b1;
            *reinterpret_cast<s8v*>(&Bsl[sr * 64 + sc + 16]) = b2;
            *reinterpret_cast<s8v*>(&Bsl[sr * 64 + sc + 24]) = b3;
            __syncthreads();
        }
#endif

#pragma unroll
        for (int kk = 0; kk < 2; ++kk) {
            s8v af[4], bf[4];
#pragma unroll
            for (int m = 0; m < 4; ++m)
                af[m] = *reinterpret_cast<const s8v*>(
                    &Asl[(wr * 64 + m * 16 + lr) * 64 + kk * 32 + lg * 8]);
#pragma unroll
            for (int n = 0; n < 4; ++n)
                bf[n] = *reinterpret_cast<const s8v*>(
                    &Bsl[(wc * 64 + n * 16 + lr) * 64 + kk * 32 + lg * 8]);
#pragma unroll
            for (int m = 0; m < 4; ++m)
#pragma unroll
                for (int n = 0; n < 4; ++n)
                    acc[m][n] = MFMA16(af[m], bf[n], acc[m][n]);
        }
        __syncthreads();   // all reads done before next stage overwrites
    }

    // epilogue: C/D layout col=lane&15, row=(lane>>4)*4+reg  [m89-verified]
    if (z < 2) {
        short* __restrict__ Y = (z == 0) ? qb : kb;
#pragma unroll
        for (int n = 0; n < 4; ++n) {
            const int col = n0 + wc * 64 + n * 16 + lr;
            const float bval = bias[col];
#pragma unroll
            for (int m = 0; m < 4; ++m) {
                const int row0 = m0 + wr * 64 + m * 16 + lg * 4;
#pragma unroll
                for (int r = 0; r < 4; ++r)
                    Y[(size_t)(row0 + r) * NU_ + col] = f2bf(acc[m][n][r] + bval);
            }
        }
    } else {
#pragma unroll
        for (int n = 0; n < 4; ++n) {
            const int col = n0 + wc * 64 + n * 16 + lr;   // 0..1023
            const float bval = bias[col];
            const int hh = col >> 6, dd = col & 63;
#pragma unroll
            for (int m = 0; m < 4; ++m) {
                const int Mi = m0 + wr * 64 + m * 16 + lg * 4;
                const int bb = Mi >> 11, t0 = Mi & 2047;
                s4v o = { f2bf(acc[m][n][0] + bval), f2bf(acc[m][n][1] + bval),
                          f2bf(acc[m][n][2] + bval), f2bf(acc[m][n][3] + bval) };
                *reinterpret_cast<s4v*>(vt + ((size_t)(bb * 16 + hh) * 64 + dd) * T_ + t0) = o;
            }
        }
    }
}

// ---------------------------------------------------------------------------
// Fused attention: loop1 = swapped QK^T + exp + in-lane rowsum + PV + `out`
// store; loop2 = score recompute + normalize + `wts` store (zero-fill above
// diagonal). rsum never leaves registers. No barriers (per-wave LDS only).
// XCD-chunked remap (1024 = 8 x 128): XCD g owns bh in [4g,4g+4) so K/V/Q
// (~3MB) stay L2-resident per XCD; heavy tiles dispatch first.
// grid (32, 32), 256 threads.
// ---------------------------------------------------------------------------
__global__ __launch_bounds__(256) void attn_fused_mfma(
    const short* __restrict__ qb, const short* __restrict__ kb,
    const short* __restrict__ vt, float* __restrict__ out,
    float* __restrict__ wts)
{
    const int lin  = blockIdx.y * 32 + blockIdx.x;
    const int virt = (lin & 7) * 128 + (lin >> 3);
    const int bh   = virt >> 5;
    const int tile = 31 - (virt & 31);         // heavy tiles first per XCD
    const int b = bh >> 4, h = bh & 15;
    const int r0 = tile * 64;
    const int t = threadIdx.x, w = t >> 6, l = t & 63;
    const int lr = l & 15, lg = l >> 4;

    __shared__ short Pl[4 * 1024];     // per-wave 16x64 bf16, swizzled

    // Q fragments (B-operand: col=lane&15=q-row, k=(lane>>4)*8+e=d)
    const short* qrow = qb + (size_t)(b * T_ + r0 + w * 16 + lr) * NU_ + h * DH_ + lg * 8;
    const s8v qf0 = *reinterpret_cast<const s8v*>(qrow);
    const s8v qf1 = *reinterpret_cast<const s8v*>(qrow + 32);

    f4 accO[4];
#pragma unroll
    for (int nt = 0; nt < 4; ++nt) accO[nt] = (f4){0.f, 0.f, 0.f, 0.f};
    float rsum = 0.f;
    const f4 zf = (f4){0.f, 0.f, 0.f, 0.f};
    const int sw = (lr & 7) << 3;      // P swizzle keyed on q-row (=lr)
    const short* kbase0 = kb + (size_t)(b * T_) * NU_ + h * DH_ + lg * 8;

    // ================= loop 1: rowsums + PV + out =================
    for (int ch = 0; ch <= tile; ++ch) {
        const int jc = ch * 64;
        const bool diag = (ch == tile);

        // swapped QK^T: s[nt][r] = S[q=lr][j = nt*16 + lg*4 + r]
        f4 s[4];
        const short* kbase = kbase0 + (size_t)jc * NU_;
#pragma unroll
        for (int nt = 0; nt < 4; ++nt) {
            const short* kr = kbase + (size_t)(nt * 16 + lr) * NU_;
            s8v kf0 = *reinterpret_cast<const s8v*>(kr);
            s8v kf1 = *reinterpret_cast<const s8v*>(kr + 32);
            f4 a = MFMA16(kf0, qf0, zf);
            s[nt] = MFMA16(kf1, qf1, a);
        }

        // exp + mask; in-lane rowsum; pack 4 bf16 -> one b64 store per nt
#pragma unroll
        for (int nt = 0; nt < 4; ++nt) {
            float e[4];
#pragma unroll
            for (int r = 0; r < 4; ++r) {
                float v = __expf(s[nt][r] * SCALE);
                if (diag && (nt * 16 + lg * 4 + r > w * 16 + lr)) v = 0.f;
                e[r] = v;
            }
            rsum += (e[0] + e[1]) + (e[2] + e[3]);
            const int colp = (nt * 16 + lg * 4) ^ sw;
            s4v pv = { f2bf(e[0]), f2bf(e[1]), f2bf(e[2]), f2bf(e[3]) };
            *reinterpret_cast<s4v*>(&Pl[w * 1024 + lr * 64 + colp]) = pv;
        }

        // PV: A = P[q=lane&15][j] (LDS b128), B = V^T rows (global 16B)
        s8v pf0 = *reinterpret_cast<const s8v*>(&Pl[w * 1024 + lr * 64 + ((lg * 8) ^ sw)]);
        s8v pf1 = *reinterpret_cast<const s8v*>(&Pl[w * 1024 + lr * 64 + ((32 + lg * 8) ^ sw)]);
#pragma unroll
        for (int nt = 0; nt < 4; ++nt) {
            const short* vr = vt + (size_t)(bh * 64 + nt * 16 + lr) * T_ + jc + lg * 8;
            s8v vf0 = *reinterpret_cast<const s8v*>(vr);
            s8v vf1 = *reinterpret_cast<const s8v*>(vr + 32);
            accO[nt] = MFMA16(pf0, vf0, accO[nt]);
            accO[nt] = MFMA16(pf1, vf1, accO[nt]);
        }
    }

    // reduce rowsums (disjoint partials at lanes lr, lr+16, lr+32, lr+48)
    rsum += __shfl_xor(rsum, 16);
    rsum += __shfl_xor(rsum, 32);      // every lane: full sum for q-row lr

    // out store: C/D rows lg*4+r -> need inv of rows lg*4+r (from lanes 0..15)
    float invr[4];
#pragma unroll
    for (int r = 0; r < 4; ++r) invr[r] = 1.f / __shfl(rsum, lg * 4 + r);
#pragma unroll
    for (int nt = 0; nt < 4; ++nt)
#pragma unroll
        for (int r = 0; r < 4; ++r)
            out[(size_t)(b * T_ + r0 + w * 16 + lg * 4 + r) * NU_ + h * DH_ + nt * 16 + lr] =
                accO[nt][r] * invr[r];

    // ================= loop 2: normalized weights =================
    const float inv = 1.f / rsum;                      // lane's own row (lr)
    float* const wrow = &wts[((size_t)bh * T_ + r0 + w * 16 + lr) * T_];

    for (int ch = 0; ch < T_ / 64; ++ch) {
        const int jc = ch * 64;
        if (ch <= tile) {
            const bool diag = (ch == tile);
            f4 s[4];
            const short* kbase = kbase0 + (size_t)jc * NU_;
#pragma unroll
            for (int nt = 0; nt < 4; ++nt) {
                const short* kr = kbase + (size_t)(nt * 16 + lr) * NU_;
                s8v kf0 = *reinterpret_cast<const s8v*>(kr);
                s8v kf1 = *reinterpret_cast<const s8v*>(kr + 32);
                f4 a = MFMA16(kf0, qf0, zf);
                s[nt] = MFMA16(kf1, qf1, a);
            }
#pragma unroll
            for (int nt = 0; nt < 4; ++nt) {
                float4 o;
                float* e = &o.x;
#pragma unroll
                for (int r = 0; r < 4; ++r) {
                    float v = __expf(s[nt][r] * SCALE) * inv;
                    if (diag && (nt * 16 + lg * 4 + r > w * 16 + lr)) v = 0.f;
                    e[r] = v;
                }
                st4(wrow + jc + nt * 16 + lg * 4, o);
            }
        } else {
            // fully above the diagonal: vectorized zero fill (block covers
            // 64 rows x 64 cols with 256 threads x 16 floats)
            float* dst = &wts[((size_t)bh * T_ + r0 + (t >> 2)) * T_ + jc + (t & 3) * 16];
            const float4 z4 = make_float4(0.f, 0.f, 0.f, 0.f);
            st4(dst + 0, z4); st4(dst + 4, z4); st4(dst + 8, z4); st4(dst + 12, z4);
        }
    }
}

// ---------------------------------------------------------------------------
extern "C" void kernel_launch(void* const* d_in, const int* in_sizes, int n_in,
                              void* d_out, int out_size, void* d_ws, size_t ws_size,
                              hipStream_t stream)
{
    const float* queries = (const float*)d_in[0];
    const float* keys    = (const float*)d_in[1];
    const float* Wq = (const float*)d_in[2];
    const float* bq = (const float*)d_in[3];
    const float* Wk = (const float*)d_in[4];
    const float* bk = (const float*)d_in[5];
    const float* Wv = (const float*)d_in[6];
    const float* bv = (const float*)d_in[7];

    float* out = (float*)d_out;                 // [B,T,NU]
    float* wts = out + OUT_ELEMS;               // [B,H,T,T]

    // workspace (bf16 shorts), total ~44 MB:
    short* qx = (short*)d_ws;                               // queries bf16 [4096][1024]
    short* kx = qx + (size_t)B_ * T_ * D_;                  // keys bf16
    short* wt = kx + (size_t)B_ * T_ * D_;                  // Wt bf16 [3][N][K]
    short* qb = wt + (size_t)3 * D_ * NU_;                  // q proj bf16 [4096][1024]
    short* kb = qb + (size_t)B_ * T_ * NU_;                 // k proj bf16
    short* vt = kb + (size_t)B_ * T_ * NU_;                 // v proj bf16, [bh][d][t]

    cvt_x_kernel<<<dim3((B_ * T_ * D_) / 2048, 2), 256, 0, stream>>>(queries, keys, qx, kx);
    cvt_w_kernel<<<dim3(16, 16, 3), 256, 0, stream>>>(Wq, Wk, Wv, wt);
    proj_mfma<<<dim3(8, 32, 3), 256, 0, stream>>>(
        qx, kx, wt, bq, bk, bv, qb, kb, vt);
    attn_fused_mfma<<<dim3(32, 32), 256, 0, stream>>>(qb, kb, vt, out, wts);
}

// Round 5
// 354.178 us; speedup vs baseline: 5.9430x; 1.2845x over previous
//
#include <hip/hip_runtime.h>
#include <cstddef>
#include <cstdint>

// Problem constants (reference: B=2, T=2048, D=1024, H=16, DH=64, NU=1024)
namespace {
constexpr int B_ = 2, T_ = 2048, D_ = 1024, H_ = 16, DH_ = 64, NU_ = 1024;
constexpr float SCALE = 0.03125f;           // NU^-0.5 = 1/32
constexpr size_t OUT_ELEMS = (size_t)B_ * T_ * NU_;   // 4,194,304
}

using f4  = __attribute__((ext_vector_type(4))) float;
using s8v = __attribute__((ext_vector_type(8))) short;   // 8 bf16 (4 VGPRs)
using s4v = __attribute__((ext_vector_type(4))) short;

#define MFMA16(a, b, c) __builtin_amdgcn_mfma_f32_16x16x32_bf16((a), (b), (c), 0, 0, 0)

__device__ __forceinline__ float4 ld4(const float* p) { return *reinterpret_cast<const float4*>(p); }
__device__ __forceinline__ void st4(float* p, const float4 v) { *reinterpret_cast<float4*>(p) = v; }
__device__ __forceinline__ short f2bf(float f) {      // fp32 -> bf16 RNE
    union { float f; uint32_t u; } v{f};
    uint32_t r = (v.u + 0x7fffu + ((v.u >> 16) & 1u)) >> 16;
    return (short)r;
}

#if __has_builtin(__builtin_amdgcn_global_load_lds)
#define HAVE_GLOAD_LDS 1
__device__ __forceinline__ void load_lds16(const void* g, void* l) {
    __builtin_amdgcn_global_load_lds(
        (const __attribute__((address_space(1))) void*)g,
        (__attribute__((address_space(3))) void*)l, 16, 0, 0);
}
#else
#define HAVE_GLOAD_LDS 0
#endif

// ---------------------------------------------------------------------------
// Convert queries/keys fp32 -> bf16 row-major. grid (N/2048, 2).
// ---------------------------------------------------------------------------
__global__ __launch_bounds__(256) void cvt_x_kernel(
    const float* __restrict__ q, const float* __restrict__ k,
    short* __restrict__ qx, short* __restrict__ kx)
{
    const float* src = blockIdx.y ? k : q;
    short* dst       = blockIdx.y ? kx : qx;
    size_t i = ((size_t)blockIdx.x * 256 + threadIdx.x) * 8;
    float4 a = ld4(src + i), b = ld4(src + i + 4);
    s8v o = { f2bf(a.x), f2bf(a.y), f2bf(a.z), f2bf(a.w),
              f2bf(b.x), f2bf(b.y), f2bf(b.z), f2bf(b.w) };
    *reinterpret_cast<s8v*>(dst + i) = o;
}

// ---------------------------------------------------------------------------
// Convert + transpose W fp32 [K][N] -> bf16 Wt [N][K]. grid (16,16,3).
// ---------------------------------------------------------------------------
__global__ __launch_bounds__(256) void cvt_w_kernel(
    const float* __restrict__ Wq, const float* __restrict__ Wk,
    const float* __restrict__ Wv, short* __restrict__ wt3)
{
    const int z = blockIdx.z;
    const float* W = (z == 0) ? Wq : (z == 1) ? Wk : Wv;
    short* dst = wt3 + (size_t)z * D_ * NU_;
    const int n0 = blockIdx.x * 64, k0 = blockIdx.y * 64;
    __shared__ float tl[64][68];
    const int rr = threadIdx.x >> 2, cc = (threadIdx.x & 3) * 16;
    const float* s = W + (size_t)(k0 + rr) * NU_ + n0 + cc;
    st4(&tl[rr][cc + 0],  ld4(s + 0));
    st4(&tl[rr][cc + 4],  ld4(s + 4));
    st4(&tl[rr][cc + 8],  ld4(s + 8));
    st4(&tl[rr][cc + 12], ld4(s + 12));
    __syncthreads();
    short* d = dst + (size_t)(n0 + rr) * D_ + k0 + cc;
#pragma unroll
    for (int c = 0; c < 4; ++c) {
        s4v o = { f2bf(tl[cc + c * 4 + 0][rr]), f2bf(tl[cc + c * 4 + 1][rr]),
                  f2bf(tl[cc + c * 4 + 2][rr]), f2bf(tl[cc + c * 4 + 3][rr]) };
        *reinterpret_cast<s4v*>(d + c * 4) = o;
    }
}

// ---------------------------------------------------------------------------
// QKV projection, bf16 MFMA: 128x128 tile, BK=64, 4 waves, global_load_lds
// width-16 into linear [128][64] LDS. XCD-chunked remap (768 = 8 x 96).
// z=0->qb, z=1->kb, z=2->vt ([bh][d][t] transposed). grid(8,32,3), 256 thr.
// ---------------------------------------------------------------------------
__global__ __launch_bounds__(256) void proj_mfma(
    const short* __restrict__ qx, const short* __restrict__ kx,
    const short* __restrict__ wt3,
    const float* __restrict__ bq, const float* __restrict__ bk,
    const float* __restrict__ bv,
    short* __restrict__ qb, short* __restrict__ kb, short* __restrict__ vt)
{
    const int lin = blockIdx.z * 256 + blockIdx.y * 8 + blockIdx.x;
    const int virt = (lin & 7) * 96 + (lin >> 3);
    const int z = virt >> 8, rem = virt & 255;
    const int m0 = (rem >> 3) * 128, n0 = (rem & 7) * 128;

    const short* __restrict__ X  = (z == 0) ? qx : kx;
    const short* __restrict__ Wt = wt3 + (size_t)z * D_ * NU_;
    const float* __restrict__ bias = (z == 0) ? bq : (z == 1) ? bk : bv;

    const int t = threadIdx.x, w = t >> 6, l = t & 63;
    const int lr = l & 15, lg = l >> 4;
    const int wr = w >> 1, wc = w & 1;

    __shared__ short Asl[128 * 64];   // [row][k] linear, 16KB
    __shared__ short Bsl[128 * 64];   // [n][k] linear, 16KB

    f4 acc[4][4];
#pragma unroll
    for (int m = 0; m < 4; ++m)
#pragma unroll
        for (int n = 0; n < 4; ++n) acc[m][n] = (f4){0.f, 0.f, 0.f, 0.f};

    for (int k0 = 0; k0 < D_; k0 += 64) {
#if HAVE_GLOAD_LDS
#pragma unroll
        for (int j = 0; j < 4; ++j) {
            const int c0 = (w * 4 + j) * 64;
            const int c  = c0 + l;
            const int row = c >> 3, qo = (c & 7) * 8;
            load_lds16(X  + (size_t)(m0 + row) * D_ + k0 + qo, (char*)Asl + (size_t)c0 * 16);
            load_lds16(Wt + (size_t)(n0 + row) * D_ + k0 + qo, (char*)Bsl + (size_t)c0 * 16);
        }
        __syncthreads();
#else
        {
            const int sr = t >> 1, sc = (t & 1) * 32;
            s8v a0 = *reinterpret_cast<const s8v*>(X  + (size_t)(m0 + sr) * D_ + k0 + sc);
            s8v a1 = *reinterpret_cast<const s8v*>(X  + (size_t)(m0 + sr) * D_ + k0 + sc + 8);
            s8v a2 = *reinterpret_cast<const s8v*>(X  + (size_t)(m0 + sr) * D_ + k0 + sc + 16);
            s8v a3 = *reinterpret_cast<const s8v*>(X  + (size_t)(m0 + sr) * D_ + k0 + sc + 24);
            s8v b0 = *reinterpret_cast<const s8v*>(Wt + (size_t)(n0 + sr) * D_ + k0 + sc);
            s8v b1 = *reinterpret_cast<const s8v*>(Wt + (size_t)(n0 + sr) * D_ + k0 + sc + 8);
            s8v b2 = *reinterpret_cast<const s8v*>(Wt + (size_t)(n0 + sr) * D_ + k0 + sc + 16);
            s8v b3 = *reinterpret_cast<const s8v*>(Wt + (size_t)(n0 + sr) * D_ + k0 + sc + 24);
            __syncthreads();
            *reinterpret_cast<s8v*>(&Asl[sr * 64 + sc])      = a0;
            *reinterpret_cast<s8v*>(&Asl[sr * 64 + sc + 8])  = a1;
            *reinterpret_cast<s8v*>(&Asl[sr * 64 + sc + 16]) = a2;
            *reinterpret_cast<s8v*>(&Asl[sr * 64 + sc + 24]) = a3;
            *reinterpret_cast<s8v*>(&Bsl[sr * 64 + sc])      = b0;
            *reinterpret_cast<s8v*>(&Bsl[sr * 64 + sc + 8])  = b1;
            *reinterpret_cast<s8v*>(&Bsl[sr * 64 + sc + 16]) = b2;
            *reinterpret_cast<s8v*>(&Bsl[sr * 64 + sc + 24]) = b3;
            __syncthreads();
        }
#endif

#pragma unroll
        for (int kk = 0; kk < 2; ++kk) {
            s8v af[4], bf[4];
#pragma unroll
            for (int m = 0; m < 4; ++m)
                af[m] = *reinterpret_cast<const s8v*>(
                    &Asl[(wr * 64 + m * 16 + lr) * 64 + kk * 32 + lg * 8]);
#pragma unroll
            for (int n = 0; n < 4; ++n)
                bf[n] = *reinterpret_cast<const s8v*>(
                    &Bsl[(wc * 64 + n * 16 + lr) * 64 + kk * 32 + lg * 8]);
#pragma unroll
            for (int m = 0; m < 4; ++m)
#pragma unroll
                for (int n = 0; n < 4; ++n)
                    acc[m][n] = MFMA16(af[m], bf[n], acc[m][n]);
        }
        __syncthreads();
    }

    if (z < 2) {
        short* __restrict__ Y = (z == 0) ? qb : kb;
#pragma unroll
        for (int n = 0; n < 4; ++n) {
            const int col = n0 + wc * 64 + n * 16 + lr;
            const float bval = bias[col];
#pragma unroll
            for (int m = 0; m < 4; ++m) {
                const int row0 = m0 + wr * 64 + m * 16 + lg * 4;
#pragma unroll
                for (int r = 0; r < 4; ++r)
                    Y[(size_t)(row0 + r) * NU_ + col] = f2bf(acc[m][n][r] + bval);
            }
        }
    } else {
#pragma unroll
        for (int n = 0; n < 4; ++n) {
            const int col = n0 + wc * 64 + n * 16 + lr;   // 0..1023
            const float bval = bias[col];
            const int hh = col >> 6, dd = col & 63;
#pragma unroll
            for (int m = 0; m < 4; ++m) {
                const int Mi = m0 + wr * 64 + m * 16 + lg * 4;
                const int bb = Mi >> 11, t0 = Mi & 2047;
                s4v o = { f2bf(acc[m][n][0] + bval), f2bf(acc[m][n][1] + bval),
                          f2bf(acc[m][n][2] + bval), f2bf(acc[m][n][3] + bval) };
                *reinterpret_cast<s4v*>(vt + ((size_t)(bb * 16 + hh) * 64 + dd) * T_ + t0) = o;
            }
        }
    }
}

// ---------------------------------------------------------------------------
// Attention pass A (PV + rowsums + out): block = 16 q-rows (g16 band), the
// block's 4 waves SPLIT the causal chunk range (wave w takes chunks w, w+4,
// ...), each accumulating partial rsum/accO. Two-barrier LDS reduction (OA
// aliases the dead P buffer) combines partials; stores out + rsws.
// grid 4096 (= 16 blocks/CU supplied, ~8 resident), 256 threads.
// XCD-chunked: XCD g owns bh in [4g,4g+4); heavy bands first.
// ---------------------------------------------------------------------------
__global__ __launch_bounds__(256) void attn_pv_mfma(
    const short* __restrict__ qb, const short* __restrict__ kb,
    const short* __restrict__ vt, float* __restrict__ rsws,
    float* __restrict__ out)
{
    const int lin = blockIdx.x;
    const int xcd = lin & 7, v = lin >> 3;
    const int bh  = xcd * 4 + (v >> 7);
    const int g16 = 127 - (v & 127);           // heavy bands dispatch first
    const int b = bh >> 4, h = bh & 15;
    const int t = threadIdx.x, w = t >> 6, l = t & 63;
    const int lr = l & 15, lg = l >> 4;
    const int tile16 = g16 >> 2;               // last (diagonal) chunk index
    const int rloc   = (g16 & 3) * 16 + lr;    // q-row pos within diag chunk

    __shared__ __align__(16) char smem[16 * 1024 + 256];
    short* Pl    = (short*)smem;               // per-wave 16x64 bf16 (loop)
    float* OA    = (float*)smem;               // 4x64x16 f32 (after barrier)
    float* rsbuf = (float*)(smem + 16 * 1024); // 4x16 partial rowsums

    // Q fragments: all 4 waves share the same 16 rows (B-operand: col=lr)
    const short* qrow = qb + (size_t)(b * T_ + g16 * 16 + lr) * NU_ + h * DH_ + lg * 8;
    const s8v qf0 = *reinterpret_cast<const s8v*>(qrow);
    const s8v qf1 = *reinterpret_cast<const s8v*>(qrow + 32);

    f4 accO[4];
#pragma unroll
    for (int nt = 0; nt < 4; ++nt) accO[nt] = (f4){0.f, 0.f, 0.f, 0.f};
    float rsum = 0.f;
    const f4 zf = (f4){0.f, 0.f, 0.f, 0.f};
    const int sw = (lr & 7) << 3;              // P swizzle keyed on q-row
    const short* kbase0 = kb + (size_t)(b * T_) * NU_ + h * DH_ + lg * 8;

    for (int ch = w; ch <= tile16; ch += 4) {
        const int jc = ch * 64;
        const bool diag = (ch == tile16);

        // swapped QK^T: s[nt][r] = S[q=lr][j = nt*16 + lg*4 + r]
        f4 s[4];
        const short* kbase = kbase0 + (size_t)jc * NU_;
#pragma unroll
        for (int nt = 0; nt < 4; ++nt) {
            const short* kr = kbase + (size_t)(nt * 16 + lr) * NU_;
            s8v kf0 = *reinterpret_cast<const s8v*>(kr);
            s8v kf1 = *reinterpret_cast<const s8v*>(kr + 32);
            f4 a = MFMA16(kf0, qf0, zf);
            s[nt] = MFMA16(kf1, qf1, a);
        }

        // exp + mask; in-lane rowsum; pack 4 bf16 -> one b64 store per nt
#pragma unroll
        for (int nt = 0; nt < 4; ++nt) {
            float e[4];
#pragma unroll
            for (int r = 0; r < 4; ++r) {
                float vv = __expf(s[nt][r] * SCALE);
                if (diag && (nt * 16 + lg * 4 + r > rloc)) vv = 0.f;
                e[r] = vv;
            }
            rsum += (e[0] + e[1]) + (e[2] + e[3]);
            const int colp = (nt * 16 + lg * 4) ^ sw;
            s4v pv = { f2bf(e[0]), f2bf(e[1]), f2bf(e[2]), f2bf(e[3]) };
            *reinterpret_cast<s4v*>(&Pl[w * 1024 + lr * 64 + colp]) = pv;
        }

        // PV: A = P[q=lane&15][j] (LDS b128), B = V^T rows (global 16B)
        s8v pf0 = *reinterpret_cast<const s8v*>(&Pl[w * 1024 + lr * 64 + ((lg * 8) ^ sw)]);
        s8v pf1 = *reinterpret_cast<const s8v*>(&Pl[w * 1024 + lr * 64 + ((32 + lg * 8) ^ sw)]);
#pragma unroll
        for (int nt = 0; nt < 4; ++nt) {
            const short* vr = vt + (size_t)(bh * 64 + nt * 16 + lr) * T_ + jc + lg * 8;
            s8v vf0 = *reinterpret_cast<const s8v*>(vr);
            s8v vf1 = *reinterpret_cast<const s8v*>(vr + 32);
            accO[nt] = MFMA16(pf0, vf0, accO[nt]);
            accO[nt] = MFMA16(pf1, vf1, accO[nt]);
        }
    }

    // in-wave rowsum combine: lanes lr,lr+16,lr+32,lr+48 hold disjoint j sets
    rsum += __shfl_xor(rsum, 16);
    rsum += __shfl_xor(rsum, 32);              // full partial for row lr

    __syncthreads();                            // all Pl reads done
    if (lg == 0) rsbuf[w * 16 + lr] = rsum;
#pragma unroll
    for (int nt = 0; nt < 4; ++nt)
        st4(&OA[(size_t)(w * 64 + l) * 16 + nt * 4], *(const float4*)&accO[nt]);
    __syncthreads();

    // cross-wave reduce: wave w produces out cols [w*16, w*16+16)
    float osum[4];
#pragma unroll
    for (int r = 0; r < 4; ++r) osum[r] = 0.f;
#pragma unroll
    for (int wv = 0; wv < 4; ++wv) {
        float4 p = *(const float4*)&OA[(size_t)(wv * 64 + l) * 16 + w * 4];
#pragma unroll
        for (int r = 0; r < 4; ++r) osum[r] += (&p.x)[r];
    }
#pragma unroll
    for (int r = 0; r < 4; ++r) {
        const int ro = lg * 4 + r;             // local row 0..15
        const float rt = rsbuf[ro] + rsbuf[16 + ro] + rsbuf[32 + ro] + rsbuf[48 + ro];
        out[(size_t)(b * T_ + g16 * 16 + ro) * NU_ + h * DH_ + w * 16 + lr] =
            osum[r] / rt;
    }
    if (w == 0 && t < 16)
        rsws[(size_t)bh * T_ + g16 * 16 + t] =
            rsbuf[t] + rsbuf[16 + t] + rsbuf[32 + t] + rsbuf[48 + t];
}

// ---------------------------------------------------------------------------
// Attention pass B (weights): block = 64 q-rows x 256 j-cols (4 chunks).
// Reads rsws; recomputes swapped QK^T; writes normalized fp32 weights
// (st4 x4 per lane per chunk) or zero-fills above the diagonal.
// grid 8192 (= 32 blocks/CU), 256 threads. Massive TLP -> store-bound.
// ---------------------------------------------------------------------------
__global__ __launch_bounds__(256) void attn_wts_mfma(
    const short* __restrict__ qb, const short* __restrict__ kb,
    const float* __restrict__ rsws, float* __restrict__ wts)
{
    const int lin = blockIdx.x;
    const int xcd = lin & 7, v = lin >> 3;
    const int bh  = xcd * 4 + (v >> 8);
    const int qt  = 31 - ((v >> 3) & 31);      // heavy q-tiles first
    const int jb  = v & 7;
    const int b = bh >> 4, h = bh & 15;
    const int r0 = qt * 64;
    const int t = threadIdx.x, w = t >> 6, l = t & 63;
    const int lr = l & 15, lg = l >> 4;

    const short* qrow = qb + (size_t)(b * T_ + r0 + w * 16 + lr) * NU_ + h * DH_ + lg * 8;
    const s8v qf0 = *reinterpret_cast<const s8v*>(qrow);
    const s8v qf1 = *reinterpret_cast<const s8v*>(qrow + 32);
    const f4 zf = (f4){0.f, 0.f, 0.f, 0.f};

    const int iRow = r0 + w * 16 + lr;          // this lane's q-row
    const float inv = 1.f / rsws[(size_t)bh * T_ + iRow];
    float* const wrow = &wts[((size_t)bh * T_ + iRow) * T_];
    const short* kbase0 = kb + (size_t)(b * T_) * NU_ + h * DH_ + lg * 8;

#pragma unroll
    for (int cx = 0; cx < 4; ++cx) {
        const int ch = jb * 4 + cx;
        const int jc = ch * 64;
        if (ch <= qt) {
            const bool diag = (ch == qt);
            f4 s[4];
            const short* kbase = kbase0 + (size_t)jc * NU_;
#pragma unroll
            for (int nt = 0; nt < 4; ++nt) {
                const short* kr = kbase + (size_t)(nt * 16 + lr) * NU_;
                s8v kf0 = *reinterpret_cast<const s8v*>(kr);
                s8v kf1 = *reinterpret_cast<const s8v*>(kr + 32);
                f4 a = MFMA16(kf0, qf0, zf);
                s[nt] = MFMA16(kf1, qf1, a);
            }
#pragma unroll
            for (int nt = 0; nt < 4; ++nt) {
                float4 o;
                float* e = &o.x;
#pragma unroll
                for (int r = 0; r < 4; ++r) {
                    float vv = __expf(s[nt][r] * SCALE) * inv;
                    if (diag && (nt * 16 + lg * 4 + r > w * 16 + lr)) vv = 0.f;
                    e[r] = vv;
                }
                st4(wrow + jc + nt * 16 + lg * 4, o);
            }
        } else {
            // fully above the diagonal: block covers 64 rows x 64 cols
            float* dst = &wts[((size_t)bh * T_ + r0 + (t >> 2)) * T_ + jc + (t & 3) * 16];
            const float4 z4 = make_float4(0.f, 0.f, 0.f, 0.f);
            st4(dst + 0, z4); st4(dst + 4, z4); st4(dst + 8, z4); st4(dst + 12, z4);
        }
    }
}

// ---------------------------------------------------------------------------
extern "C" void kernel_launch(void* const* d_in, const int* in_sizes, int n_in,
                              void* d_out, int out_size, void* d_ws, size_t ws_size,
                              hipStream_t stream)
{
    const float* queries = (const float*)d_in[0];
    const float* keys    = (const float*)d_in[1];
    const float* Wq = (const float*)d_in[2];
    const float* bq = (const float*)d_in[3];
    const float* Wk = (const float*)d_in[4];
    const float* bk = (const float*)d_in[5];
    const float* Wv = (const float*)d_in[6];
    const float* bv = (const float*)d_in[7];

    float* out = (float*)d_out;                 // [B,T,NU]
    float* wts = out + OUT_ELEMS;               // [B,H,T,T]

    // workspace (bf16 shorts unless noted), total ~44.3 MB:
    short* qx = (short*)d_ws;                               // queries bf16 [4096][1024]
    short* kx = qx + (size_t)B_ * T_ * D_;                  // keys bf16
    short* wt = kx + (size_t)B_ * T_ * D_;                  // Wt bf16 [3][N][K]
    short* qb = wt + (size_t)3 * D_ * NU_;                  // q proj bf16 [4096][1024]
    short* kb = qb + (size_t)B_ * T_ * NU_;                 // k proj bf16
    short* vt = kb + (size_t)B_ * T_ * NU_;                 // v proj bf16, [bh][d][t]
    float* rsws = (float*)(vt + (size_t)B_ * T_ * NU_);     // rowsums [bh][t]

    cvt_x_kernel<<<dim3((B_ * T_ * D_) / 2048, 2), 256, 0, stream>>>(queries, keys, qx, kx);
    cvt_w_kernel<<<dim3(16, 16, 3), 256, 0, stream>>>(Wq, Wk, Wv, wt);
    proj_mfma<<<dim3(8, 32, 3), 256, 0, stream>>>(
        qx, kx, wt, bq, bk, bv, qb, kb, vt);
    attn_pv_mfma<<<dim3(4096), 256, 0, stream>>>(qb, kb, vt, rsws, out);
    attn_wts_mfma<<<dim3(8192), 256, 0, stream>>>(qb, kb, rsws, wts);
}